// Round 1
// baseline (811.940 us; speedup 1.0000x reference)
//
#include <hip/hip_runtime.h>
#include <cstdint>
#include <cstddef>

#define NN 50000
#define NE 600000
#define FIN 64
#define HID 128
#define NCLS 10
#define NLAYER 3

// ---------------------------------------------------------------- CSR build
__global__ __launch_bounds__(256) void k_count(const int* __restrict__ edst,
                                               int* __restrict__ counts) {
    int e = blockIdx.x * 256 + threadIdx.x;
    if (e < NE) atomicAdd(&counts[edst[e]], 1);
}

__global__ __launch_bounds__(512) void k_scan1(const int* __restrict__ counts,
                                               int* __restrict__ row_ptr,
                                               int* __restrict__ partials, int n) {
    __shared__ int sm[512];
    int tid = threadIdx.x;
    int i = blockIdx.x * 512 + tid;
    int v = (i < n) ? counts[i] : 0;
    sm[tid] = v;
    __syncthreads();
    #pragma unroll
    for (int off = 1; off < 512; off <<= 1) {
        int t = (tid >= off) ? sm[tid - off] : 0;
        __syncthreads();
        sm[tid] += t;
        __syncthreads();
    }
    if (i < n) row_ptr[i] = sm[tid] - v;          // exclusive within block
    if (tid == 511) partials[blockIdx.x] = sm[511];
}

__global__ void k_scan2(int* __restrict__ partials, int nb) {
    if (threadIdx.x == 0 && blockIdx.x == 0) {
        int run = 0;
        for (int i = 0; i < nb; ++i) { int t = partials[i]; partials[i] = run; run += t; }
    }
}

__global__ __launch_bounds__(512) void k_scan3(int* __restrict__ row_ptr,
                                               const int* __restrict__ partials, int n) {
    int i = blockIdx.x * 512 + threadIdx.x;
    if (i < n) row_ptr[i] += partials[blockIdx.x];
}

__global__ __launch_bounds__(256) void k_fill(const int* __restrict__ edst,
                                              int* __restrict__ cursor,
                                              const int* __restrict__ row_ptr,
                                              int* __restrict__ eidx) {
    int e = blockIdx.x * 256 + threadIdx.x;
    if (e < NE) {
        int d = edst[e];
        int pos = atomicAdd(&cursor[d], 1);
        eidx[row_ptr[d] + pos] = e;
    }
}

// ---------------------------------------------------------------- GEMM (fp32)
// out[r, sel*128 + c] = sum_k A[r,k] * W[k,c] + B[c]   (optional relu)
// Block tile 128 rows x 128 cols, K processed in 64-wide halves (64KB LDS).
template <int K, int RELU>
__global__ __launch_bounds__(256) void k_gemm(
    const float* __restrict__ A, int nrows,
    const float* __restrict__ W0, const float* __restrict__ W1,
    const float* __restrict__ W2, const float* __restrict__ W3,
    const float* __restrict__ B0, const float* __restrict__ B1,
    const float* __restrict__ B2, const float* __restrict__ B3,
    float* __restrict__ out, int ldo)
{
    __shared__ float As[64 * 128];   // [k][row]  (transposed)
    __shared__ float Bs[64 * 128];   // [k][col]
    const int tid = threadIdx.x;
    const int sel = blockIdx.y;
    const float* W; const float* Bv;
    if (sel == 0)      { W = W0; Bv = B0; }
    else if (sel == 1) { W = W1; Bv = B1; }
    else if (sel == 2) { W = W2; Bv = B2; }
    else               { W = W3; Bv = B3; }
    const int row0 = blockIdx.x * 128;
    const int tx = tid & 15;
    const int ty = tid >> 4;

    float acc[8][8];
    #pragma unroll
    for (int i = 0; i < 8; ++i)
        #pragma unroll
        for (int j = 0; j < 8; ++j) acc[i][j] = 0.f;

    for (int kb = 0; kb < K; kb += 64) {
        if (kb) __syncthreads();
        // stage A[row0..row0+127, kb..kb+63] transposed -> As[k][row]
        #pragma unroll
        for (int i = 0; i < 8; ++i) {
            int fi = tid + i * 256;          // 2048 float4s
            int r  = fi >> 4;                // /16
            int k4 = (fi & 15) * 4;
            float4 v = make_float4(0.f, 0.f, 0.f, 0.f);
            if (row0 + r < nrows)
                v = *(const float4*)(A + (size_t)(row0 + r) * K + kb + k4);
            As[(k4 + 0) * 128 + r] = v.x;
            As[(k4 + 1) * 128 + r] = v.y;
            As[(k4 + 2) * 128 + r] = v.z;
            As[(k4 + 3) * 128 + r] = v.w;
        }
        // stage W[kb..kb+63, 0..127] -> Bs[k][col]
        #pragma unroll
        for (int i = 0; i < 8; ++i) {
            int fi = tid + i * 256;
            int k  = fi >> 5;
            int c4 = (fi & 31) * 4;
            *(float4*)(Bs + k * 128 + c4) = *(const float4*)(W + (size_t)(kb + k) * HID + c4);
        }
        __syncthreads();
        #pragma unroll 4
        for (int k = 0; k < 64; ++k) {
            float4 a0 = *(const float4*)(As + k * 128 + ty * 4);
            float4 a1 = *(const float4*)(As + k * 128 + 64 + ty * 4);
            float4 b0 = *(const float4*)(Bs + k * 128 + tx * 4);
            float4 b1 = *(const float4*)(Bs + k * 128 + 64 + tx * 4);
            float av[8] = {a0.x, a0.y, a0.z, a0.w, a1.x, a1.y, a1.z, a1.w};
            float bw[8] = {b0.x, b0.y, b0.z, b0.w, b1.x, b1.y, b1.z, b1.w};
            #pragma unroll
            for (int i = 0; i < 8; ++i)
                #pragma unroll
                for (int j = 0; j < 8; ++j)
                    acc[i][j] = fmaf(av[i], bw[j], acc[i][j]);
        }
    }
    // epilogue: rows {ty*4+i, 64+ty*4+i}, cols {tx*4+j, 64+tx*4+j}
    #pragma unroll
    for (int i = 0; i < 8; ++i) {
        int r = row0 + ((i < 4) ? (ty * 4 + i) : (64 + ty * 4 + (i - 4)));
        if (r >= nrows) continue;
        #pragma unroll
        for (int jh = 0; jh < 2; ++jh) {
            float4 o;
            float* op = (float*)&o;
            #pragma unroll
            for (int j = 0; j < 4; ++j) {
                int c = jh * 64 + tx * 4 + j;
                float val = acc[i][jh * 4 + j] + Bv[c];
                if (RELU) val = fmaxf(val, 0.f);
                op[j] = val;
            }
            *(float4*)(out + (size_t)r * ldo + sel * HID + jh * 64 + tx * 4) = o;
        }
    }
}

// ---------------------------------------------------------------- fused attention
// One wave per destination node. out4 row layout: [q(128) | k(128) | v(128) | hs(128)]
// Online softmax over incoming edges, then +hs, LayerNorm, ReLU -> hout.
__global__ __launch_bounds__(256) void k_attn(
    const float* __restrict__ out4,
    const int* __restrict__ esrc,
    const float* __restrict__ dist,
    const float* __restrict__ We,        // [128] for this layer
    const int* __restrict__ row_ptr,
    const int* __restrict__ counts,
    const int* __restrict__ eidx,
    const float* __restrict__ lng,
    const float* __restrict__ lnb,
    float* __restrict__ hout, int nnodes)
{
    const int wid  = threadIdx.x >> 6;
    const int lane = threadIdx.x & 63;
    const int n = blockIdx.x * 4 + wid;
    if (n >= nnodes) return;
    const int c0 = lane * 2;

    const float* rowq = out4 + (size_t)n * 512;
    const float q0 = rowq[c0],       q1 = rowq[c0 + 1];
    const float hs0 = rowq[384 + c0], hs1 = rowq[384 + c0 + 1];
    const float we0 = We[c0], we1 = We[c0 + 1];

    float m = -INFINITY, s = 0.f, a0 = 0.f, a1 = 0.f;
    const int beg = row_ptr[n];
    const int cnt = counts[n];
    for (int i = 0; i < cnt; ++i) {
        int e = eidx[beg + i];
        int src = esrc[e];
        float d = dist[e];
        const float* rk = out4 + (size_t)src * 512;
        float e0 = d * we0, e1 = d * we1;
        float k0 = rk[128 + c0] + e0, k1 = rk[128 + c0 + 1] + e1;
        float p = q0 * k0 + q1 * k1;
        // per-head (8 lanes = 16 dims) reduction
        p += __shfl_xor(p, 1);
        p += __shfl_xor(p, 2);
        p += __shfl_xor(p, 4);
        p *= 0.25f;                               // / sqrt(16)
        float mn = fmaxf(m, p);
        float sc = __expf(m - mn);                // exp(-inf)=0 on first edge
        float w  = __expf(p - mn);
        s = s * sc + w;
        float v0 = rk[256 + c0] + e0, v1 = rk[256 + c0 + 1] + e1;
        a0 = a0 * sc + v0 * w;
        a1 = a1 * sc + v1 * w;
        m = mn;
    }
    float inv = 1.f / (s + 1e-16f);
    float o0 = a0 * inv + hs0;
    float o1 = a1 * inv + hs1;

    // LayerNorm over 128 features (2 per lane) + ReLU
    float t = o0 + o1;
    #pragma unroll
    for (int off = 1; off < 64; off <<= 1) t += __shfl_xor(t, off);
    float mean = t * 0.0078125f;
    float d0 = o0 - mean, d1 = o1 - mean;
    float vv = d0 * d0 + d1 * d1;
    #pragma unroll
    for (int off = 1; off < 64; off <<= 1) vv += __shfl_xor(vv, off);
    float rstd = rsqrtf(vv * 0.0078125f + 1e-5f);
    float y0 = fmaxf(d0 * rstd * lng[c0] + lnb[c0], 0.f);
    float y1 = fmaxf(d1 * rstd * lng[c0 + 1] + lnb[c0 + 1], 0.f);
    hout[(size_t)n * HID + c0]     = y0;
    hout[(size_t)n * HID + c0 + 1] = y1;
}

// ---------------------------------------------------------------- fc_after + log_softmax
__global__ __launch_bounds__(256) void k_final(
    const float* __restrict__ h,
    const float* __restrict__ Wa,      // [128][10]
    const float* __restrict__ ba,
    float* __restrict__ out, int nnodes)
{
    const int wid  = threadIdx.x >> 6;
    const int lane = threadIdx.x & 63;
    const int n = blockIdx.x * 4 + wid;
    if (n >= nnodes) return;
    const int c0 = lane * 2;
    const float h0 = h[(size_t)n * HID + c0];
    const float h1 = h[(size_t)n * HID + c0 + 1];
    float logit[NCLS];
    #pragma unroll
    for (int c = 0; c < NCLS; ++c) {
        float p = h0 * Wa[c0 * NCLS + c] + h1 * Wa[(c0 + 1) * NCLS + c];
        #pragma unroll
        for (int off = 1; off < 64; off <<= 1) p += __shfl_xor(p, off);
        logit[c] = p + ba[c];
    }
    float mx = logit[0];
    #pragma unroll
    for (int c = 1; c < NCLS; ++c) mx = fmaxf(mx, logit[c]);
    float sum = 0.f;
    #pragma unroll
    for (int c = 0; c < NCLS; ++c) sum += __expf(logit[c] - mx);
    float lse = mx + __logf(sum);
    if (lane == 0) {
        #pragma unroll
        for (int c = 0; c < NCLS; ++c) out[(size_t)n * NCLS + c] = logit[c] - lse;
    }
}

// ---------------------------------------------------------------- launch
extern "C" void kernel_launch(void* const* d_in, const int* in_sizes, int n_in,
                              void* d_out, int out_size, void* d_ws, size_t ws_size,
                              hipStream_t stream)
{
    const float* x    = (const float*)d_in[0];
    const int*   ei   = (const int*)d_in[1];
    const float* dist = (const float*)d_in[2];
    const float* Wq   = (const float*)d_in[3];
    const float* bq   = (const float*)d_in[4];
    const float* Wk   = (const float*)d_in[5];
    const float* bk   = (const float*)d_in[6];
    const float* Wv   = (const float*)d_in[7];
    const float* bv   = (const float*)d_in[8];
    const float* We   = (const float*)d_in[9];
    const float* Wsk  = (const float*)d_in[10];
    const float* bs   = (const float*)d_in[11];
    const float* lng  = (const float*)d_in[12];
    const float* lnb  = (const float*)d_in[13];
    const float* Wbe  = (const float*)d_in[14];
    const float* bbe  = (const float*)d_in[15];
    const float* Waf  = (const float*)d_in[16];
    const float* baf  = (const float*)d_in[17];
    float* out = (float*)d_out;
    const int* esrc = ei;
    const int* edst = ei + NE;

    char* ws = (char*)d_ws;
    float* h    = (float*)ws;                         // 25.6 MB
    float* out4 = (float*)(ws + 25600000);            // 102.4 MB
    char* p = ws + 25600000 + 102400000;
    int* counts   = (int*)p;  p += 50048 * 4;
    int* cursor   = (int*)p;  p += 50048 * 4;
    int* row_ptr  = (int*)p;  p += 50048 * 4;
    int* partials = (int*)p;  p += 1024 * 4;
    int* eidx     = (int*)p;  p += (size_t)NE * 4;

    // CSR build (edge_index is identical every call; rebuilt each call for determinism)
    hipMemsetAsync(counts, 0, NN * sizeof(int), stream);
    hipMemsetAsync(cursor, 0, NN * sizeof(int), stream);
    k_count<<<(NE + 255) / 256, 256, 0, stream>>>(edst, counts);
    int nsb = (NN + 511) / 512;   // 98
    k_scan1<<<nsb, 512, 0, stream>>>(counts, row_ptr, partials, NN);
    k_scan2<<<1, 64, 0, stream>>>(partials, nsb);
    k_scan3<<<nsb, 512, 0, stream>>>(row_ptr, partials, NN);
    k_fill<<<(NE + 255) / 256, 256, 0, stream>>>(edst, cursor, row_ptr, eidx);

    // h = relu(x @ W_before + b_before)
    k_gemm<64, 1><<<dim3(391, 1), 256, 0, stream>>>(x, NN,
        Wbe, Wbe, Wbe, Wbe, bbe, bbe, bbe, bbe, h, HID);

    for (int l = 0; l < NLAYER; ++l) {
        k_gemm<128, 0><<<dim3(391, 4), 256, 0, stream>>>(h, NN,
            Wq + (size_t)l * HID * HID, Wk + (size_t)l * HID * HID,
            Wv + (size_t)l * HID * HID, Wsk + (size_t)l * HID * HID,
            bq + l * HID, bk + l * HID, bv + l * HID, bs + l * HID,
            out4, 4 * HID);
        k_attn<<<(NN + 3) / 4, 256, 0, stream>>>(out4, esrc, dist, We + l * HID,
            row_ptr, counts, eidx, lng + l * HID, lnb + l * HID, h, NN);
    }
    k_final<<<(NN + 3) / 4, 256, 0, stream>>>(h, Waf, baf, out, NN);
}

// Round 2
// 601.345 us; speedup vs baseline: 1.3502x; 1.3502x over previous
//
#include <hip/hip_runtime.h>
#include <cstdint>
#include <cstddef>

#define NN 50000
#define NE 600000
#define FIN 64
#define HID 128
#define NCLS 10
#define NLAYER 3

typedef __bf16 bf16x8 __attribute__((ext_vector_type(8)));
typedef float f32x4 __attribute__((ext_vector_type(4)));

__device__ __forceinline__ unsigned short f2bf(float f) {
    unsigned int u = __builtin_bit_cast(unsigned int, f);
    u += 0x7fffu + ((u >> 16) & 1u);
    return (unsigned short)(u >> 16);
}
__device__ __forceinline__ float bf2f(unsigned short s) {
    unsigned int u = ((unsigned int)s) << 16;
    return __builtin_bit_cast(float, u);
}

// ---------------------------------------------------------------- CSR build
__global__ __launch_bounds__(256) void k_count(const int* __restrict__ edst,
                                               int* __restrict__ counts) {
    int e = blockIdx.x * 256 + threadIdx.x;
    if (e < NE) atomicAdd(&counts[edst[e]], 1);
}

__global__ __launch_bounds__(512) void k_scan1(const int* __restrict__ counts,
                                               int* __restrict__ row_ptr,
                                               int* __restrict__ partials, int n) {
    __shared__ int sm[512];
    int tid = threadIdx.x;
    int i = blockIdx.x * 512 + tid;
    int v = (i < n) ? counts[i] : 0;
    sm[tid] = v;
    __syncthreads();
    #pragma unroll
    for (int off = 1; off < 512; off <<= 1) {
        int t = (tid >= off) ? sm[tid - off] : 0;
        __syncthreads();
        sm[tid] += t;
        __syncthreads();
    }
    if (i < n) row_ptr[i] = sm[tid] - v;
    if (tid == 511) partials[blockIdx.x] = sm[511];
}

__global__ __launch_bounds__(128) void k_scan2(int* __restrict__ partials, int nb) {
    __shared__ int sm[128];
    int t = threadIdx.x;
    int v = (t < nb) ? partials[t] : 0;
    sm[t] = v;
    __syncthreads();
    #pragma unroll
    for (int off = 1; off < 128; off <<= 1) {
        int x = (t >= off) ? sm[t - off] : 0;
        __syncthreads();
        sm[t] += x;
        __syncthreads();
    }
    if (t < nb) partials[t] = sm[t] - v;   // exclusive
}

__global__ __launch_bounds__(512) void k_scan3(int* __restrict__ row_ptr,
                                               const int* __restrict__ partials, int n) {
    int i = blockIdx.x * 512 + threadIdx.x;
    if (i < n) row_ptr[i] += partials[blockIdx.x];
}

__global__ __launch_bounds__(256) void k_fill(const int* __restrict__ esrc,
                                              const int* __restrict__ edst,
                                              const float* __restrict__ dist,
                                              int* __restrict__ cursor,
                                              const int* __restrict__ row_ptr,
                                              int* __restrict__ srcs,
                                              float* __restrict__ dists) {
    int e = blockIdx.x * 256 + threadIdx.x;
    if (e < NE) {
        int d = edst[e];
        int pos = atomicAdd(&cursor[d], 1);
        int slot = row_ptr[d] + pos;
        srcs[slot] = esrc[e];
        dists[slot] = dist[e];
    }
}

// ---------------------------------------------------------------- converts
__global__ __launch_bounds__(256) void k_cvt(const float* __restrict__ in,
                                             unsigned short* __restrict__ out, int n4) {
    int i = blockIdx.x * 256 + threadIdx.x;
    if (i < n4) {
        float4 v = *(const float4*)(in + (size_t)i * 4);
        ushort4 o;
        o.x = f2bf(v.x); o.y = f2bf(v.y); o.z = f2bf(v.z); o.w = f2bf(v.w);
        *(ushort4*)(out + (size_t)i * 4) = o;
    }
}

// transpose 12 layer weight mats [128][128] f32 -> bf16 [col][k]
__global__ __launch_bounds__(256) void k_tw12(const float* __restrict__ Wq,
                                              const float* __restrict__ Wk,
                                              const float* __restrict__ Wv,
                                              const float* __restrict__ Ws,
                                              unsigned short* __restrict__ Wt) {
    int m = blockIdx.x >> 6;            // 0..11
    int l = m >> 2, which = m & 3;
    const float* src;
    if (which == 0) src = Wq; else if (which == 1) src = Wk;
    else if (which == 2) src = Wv; else src = Ws;
    src += (size_t)l * HID * HID;
    int idx = (blockIdx.x & 63) * 256 + threadIdx.x;   // 0..16383
    int c = idx >> 7, k = idx & 127;
    Wt[(size_t)m * 16384 + (size_t)c * 128 + k] = f2bf(src[(size_t)k * 128 + c]);
}

// transpose W_before [64][128] f32 -> bf16 [128][64]
__global__ __launch_bounds__(256) void k_twb(const float* __restrict__ W,
                                             unsigned short* __restrict__ Wt) {
    int idx = blockIdx.x * 256 + threadIdx.x;   // 0..8191
    int c = idx >> 6, k = idx & 63;
    Wt[(size_t)c * 64 + k] = f2bf(W[(size_t)k * 128 + c]);
}

// ---------------------------------------------------------------- MFMA GEMM
// out[r, c] = sum_k A[r,k] * W[k,c] + bias[c]
// A: bf16 row-major [nrows][BK]; Wt: bf16 [128][BK] (= W transposed)
// MODE: 0 -> f32 outf (qs); 3 -> f32 outf (hs);
//       1 -> bf16 kv k-part; 2 -> bf16 kv v-part; 4 -> relu bf16 outb (hb)
template <int BK, int MODE>
__global__ __launch_bounds__(256, 2) void k_mgemm(
    const unsigned short* __restrict__ Ab, int nrows,
    const unsigned short* __restrict__ Wt,
    const float* __restrict__ bias,
    float* __restrict__ outf,
    unsigned short* __restrict__ outb)
{
    constexpr int ROWB = BK * 2 + 16;               // padded row bytes
    __shared__ char lds[(64 + 128) * ROWB];
    char* As = lds;
    char* Bs = lds + 64 * ROWB;
    const int tid = threadIdx.x;
    const int row0 = blockIdx.x * 64;

    // stage A tile [64][BK]
    {
        constexpr int CPR = BK / 8;                  // 16B chunks per row
        constexpr int CHUNKS = 64 * CPR;
        #pragma unroll
        for (int c = tid; c < CHUNKS; c += 256) {
            int r = c / CPR, o = c % CPR;
            uint4 v = make_uint4(0, 0, 0, 0);
            if (row0 + r < nrows)
                v = *(const uint4*)(Ab + (size_t)(row0 + r) * BK + o * 8);
            *(uint4*)(As + r * ROWB + o * 16) = v;
        }
    }
    // stage Wt [128][BK]
    {
        constexpr int CPR = BK / 8;
        constexpr int CHUNKS = 128 * CPR;
        #pragma unroll
        for (int c = tid; c < CHUNKS; c += 256) {
            int r = c / CPR, o = c % CPR;
            *(uint4*)(Bs + r * ROWB + o * 16) = *(const uint4*)(Wt + (size_t)r * BK + o * 8);
        }
    }
    __syncthreads();

    const int w = tid >> 6, lane = tid & 63;
    const int arow = (w << 4) + (lane & 15);
    const int koff = (lane >> 4) * 16;               // byte offset within 64B k-block

    bf16x8 a[BK / 32];
    #pragma unroll
    for (int kb = 0; kb < BK / 32; ++kb)
        a[kb] = *(const bf16x8*)(As + arow * ROWB + kb * 64 + koff);

    const int rbase = row0 + (w << 4) + ((lane >> 4) << 2);
    #pragma unroll
    for (int ct = 0; ct < 8; ++ct) {
        f32x4 acc = {0.f, 0.f, 0.f, 0.f};
        const int bcol = ct * 16 + (lane & 15);
        #pragma unroll
        for (int kb = 0; kb < BK / 32; ++kb) {
            bf16x8 b = *(const bf16x8*)(Bs + bcol * ROWB + kb * 64 + koff);
            acc = __builtin_amdgcn_mfma_f32_16x16x32_bf16(a[kb], b, acc, 0, 0, 0);
        }
        const float bv = bias[bcol];
        #pragma unroll
        for (int i = 0; i < 4; ++i) {
            int r = rbase + i;
            if (r >= nrows) continue;
            float val = acc[i] + bv;
            if (MODE == 0 || MODE == 3) {
                outf[(size_t)r * 128 + bcol] = val;
            } else if (MODE == 4) {
                outb[(size_t)r * 128 + bcol] = f2bf(fmaxf(val, 0.f));
            } else {
                // kv row layout: pair j holds {k[2j],k[2j+1],v[2j],v[2j+1]}
                int off = (bcol >> 1) * 4 + (bcol & 1) + (MODE == 2 ? 2 : 0);
                outb[(size_t)r * 256 + off] = f2bf(val);
            }
        }
    }
}

// ---------------------------------------------------------------- fused attention
__global__ __launch_bounds__(256) void k_attn(
    const float* __restrict__ qs,
    const float* __restrict__ hs,
    const unsigned short* __restrict__ kv,
    const int* __restrict__ srcs,
    const float* __restrict__ dists,
    const float* __restrict__ We,
    const int* __restrict__ row_ptr,
    const int* __restrict__ counts,
    const float* __restrict__ lng,
    const float* __restrict__ lnb,
    unsigned short* __restrict__ hb, int nnodes)
{
    const int wid = threadIdx.x >> 6;
    const int lane = threadIdx.x & 63;
    const int n = blockIdx.x * 4 + wid;
    if (n >= nnodes) return;
    const int c0 = lane * 2;

    const float q0 = qs[(size_t)n * 128 + c0];
    const float q1 = qs[(size_t)n * 128 + c0 + 1];
    const float hs0 = hs[(size_t)n * 128 + c0];
    const float hs1 = hs[(size_t)n * 128 + c0 + 1];
    const float we0 = We[c0], we1 = We[c0 + 1];

    float m = -INFINITY, s = 0.f, a0 = 0.f, a1 = 0.f;
    const int beg = row_ptr[n];
    const int cnt = counts[n];

    ushort4 u_c;
    float d_c = 0.f;
    if (cnt > 0) {
        int s0 = srcs[beg];
        d_c = dists[beg];
        u_c = *(const ushort4*)(kv + (size_t)s0 * 256 + lane * 4);
    }
    for (int i = 0; i < cnt; ++i) {
        ushort4 u = u_c;
        float d = d_c;
        if (i + 1 < cnt) {
            int sn = srcs[beg + i + 1];
            d_c = dists[beg + i + 1];
            u_c = *(const ushort4*)(kv + (size_t)sn * 256 + lane * 4);
        }
        float e0 = d * we0, e1 = d * we1;
        float k0 = bf2f(u.x) + e0, k1 = bf2f(u.y) + e1;
        float p = q0 * k0 + q1 * k1;
        p += __shfl_xor(p, 1);
        p += __shfl_xor(p, 2);
        p += __shfl_xor(p, 4);
        p *= 0.25f;                               // / sqrt(16)
        float mn = fmaxf(m, p);
        float sc = __expf(m - mn);
        float wgt = __expf(p - mn);
        s = s * sc + wgt;
        float v0 = bf2f(u.z) + e0, v1 = bf2f(u.w) + e1;
        a0 = a0 * sc + v0 * wgt;
        a1 = a1 * sc + v1 * wgt;
        m = mn;
    }
    float inv = 1.f / (s + 1e-16f);
    float o0 = a0 * inv + hs0;
    float o1 = a1 * inv + hs1;

    // LayerNorm over 128 features + ReLU -> bf16
    float t = o0 + o1;
    #pragma unroll
    for (int off = 1; off < 64; off <<= 1) t += __shfl_xor(t, off);
    float mean = t * 0.0078125f;
    float d0 = o0 - mean, d1 = o1 - mean;
    float vv = d0 * d0 + d1 * d1;
    #pragma unroll
    for (int off = 1; off < 64; off <<= 1) vv += __shfl_xor(vv, off);
    float rstd = rsqrtf(vv * 0.0078125f + 1e-5f);
    float y0 = fmaxf(d0 * rstd * lng[c0] + lnb[c0], 0.f);
    float y1 = fmaxf(d1 * rstd * lng[c0 + 1] + lnb[c0 + 1], 0.f);
    ushort2 o;
    o.x = f2bf(y0);
    o.y = f2bf(y1);
    *(ushort2*)(hb + (size_t)n * 128 + c0) = o;
}

// ---------------------------------------------------------------- fc_after + log_softmax
__global__ __launch_bounds__(256) void k_final(
    const unsigned short* __restrict__ hb,
    const float* __restrict__ Wa,      // [128][10]
    const float* __restrict__ ba,
    float* __restrict__ out, int nnodes)
{
    const int wid = threadIdx.x >> 6;
    const int lane = threadIdx.x & 63;
    const int n = blockIdx.x * 4 + wid;
    if (n >= nnodes) return;
    const int c0 = lane * 2;
    const float h0 = bf2f(hb[(size_t)n * 128 + c0]);
    const float h1 = bf2f(hb[(size_t)n * 128 + c0 + 1]);
    float logit[NCLS];
    #pragma unroll
    for (int c = 0; c < NCLS; ++c) {
        float p = h0 * Wa[c0 * NCLS + c] + h1 * Wa[(c0 + 1) * NCLS + c];
        #pragma unroll
        for (int off = 1; off < 64; off <<= 1) p += __shfl_xor(p, off);
        logit[c] = p + ba[c];
    }
    float mx = logit[0];
    #pragma unroll
    for (int c = 1; c < NCLS; ++c) mx = fmaxf(mx, logit[c]);
    float sum = 0.f;
    #pragma unroll
    for (int c = 0; c < NCLS; ++c) sum += __expf(logit[c] - mx);
    float lse = mx + __logf(sum);
    if (lane == 0) {
        #pragma unroll
        for (int c = 0; c < NCLS; ++c) out[(size_t)n * NCLS + c] = logit[c] - lse;
    }
}

// ---------------------------------------------------------------- launch
extern "C" void kernel_launch(void* const* d_in, const int* in_sizes, int n_in,
                              void* d_out, int out_size, void* d_ws, size_t ws_size,
                              hipStream_t stream)
{
    const float* x    = (const float*)d_in[0];
    const int*   ei   = (const int*)d_in[1];
    const float* dist = (const float*)d_in[2];
    const float* Wq   = (const float*)d_in[3];
    const float* bq   = (const float*)d_in[4];
    const float* Wk   = (const float*)d_in[5];
    const float* bk   = (const float*)d_in[6];
    const float* Wv   = (const float*)d_in[7];
    const float* bv   = (const float*)d_in[8];
    const float* We   = (const float*)d_in[9];
    const float* Wsk  = (const float*)d_in[10];
    const float* bs   = (const float*)d_in[11];
    const float* lng  = (const float*)d_in[12];
    const float* lnb  = (const float*)d_in[13];
    const float* Wbe  = (const float*)d_in[14];
    const float* bbe  = (const float*)d_in[15];
    const float* Waf  = (const float*)d_in[16];
    const float* baf  = (const float*)d_in[17];
    float* out = (float*)d_out;
    const int* esrc = ei;
    const int* edst = ei + NE;

    char* ws = (char*)d_ws;
    size_t off = 0;
    float* qs = (float*)(ws + off);            off += 25600000;
    float* hsv = (float*)(ws + off);           off += 25600000;
    unsigned short* kv = (unsigned short*)(ws + off);  off += 25600000;
    unsigned short* hb = (unsigned short*)(ws + off);  off += 12800000;
    unsigned short* xb = (unsigned short*)(ws + off);  off += 6400000;
    unsigned short* Wt12 = (unsigned short*)(ws + off); off += 393216;
    unsigned short* Wbt = (unsigned short*)(ws + off);  off += 16384;
    int* counts   = (int*)(ws + off);  off += 200192;
    int* cursor   = (int*)(ws + off);  off += 200192;
    int* row_ptr  = (int*)(ws + off);  off += 200192;
    int* partials = (int*)(ws + off);  off += 512;
    int* srcs     = (int*)(ws + off);  off += 2400000;
    float* dists  = (float*)(ws + off); off += 2400000;

    // CSR build
    hipMemsetAsync(counts, 0, NN * sizeof(int), stream);
    hipMemsetAsync(cursor, 0, NN * sizeof(int), stream);
    k_count<<<(NE + 255) / 256, 256, 0, stream>>>(edst, counts);
    int nsb = (NN + 511) / 512;   // 98
    k_scan1<<<nsb, 512, 0, stream>>>(counts, row_ptr, partials, NN);
    k_scan2<<<1, 128, 0, stream>>>(partials, nsb);
    k_scan3<<<nsb, 512, 0, stream>>>(row_ptr, partials, NN);
    k_fill<<<(NE + 255) / 256, 256, 0, stream>>>(esrc, edst, dist, cursor, row_ptr, srcs, dists);

    // converts
    k_cvt<<<(NN * FIN / 4 + 255) / 256, 256, 0, stream>>>(x, xb, NN * FIN / 4);
    k_tw12<<<12 * 64, 256, 0, stream>>>(Wq, Wk, Wv, Wsk, Wt12);
    k_twb<<<32, 256, 0, stream>>>(Wbe, Wbt);

    const int ngb = (NN + 63) / 64;   // 782

    // h = relu(x @ W_before + b_before)  -> hb (bf16)
    k_mgemm<64, 4><<<ngb, 256, 0, stream>>>(xb, NN, Wbt, bbe, nullptr, hb);

    for (int l = 0; l < NLAYER; ++l) {
        const unsigned short* wt = Wt12 + (size_t)l * 4 * 16384;
        k_mgemm<128, 0><<<ngb, 256, 0, stream>>>(hb, NN, wt,            bq + l * HID, qs, nullptr);
        k_mgemm<128, 1><<<ngb, 256, 0, stream>>>(hb, NN, wt + 16384,    bk + l * HID, nullptr, kv);
        k_mgemm<128, 2><<<ngb, 256, 0, stream>>>(hb, NN, wt + 2 * 16384, bv + l * HID, nullptr, kv);
        k_mgemm<128, 3><<<ngb, 256, 0, stream>>>(hb, NN, wt + 3 * 16384, bs + l * HID, hsv, nullptr);
        k_attn<<<(NN + 3) / 4, 256, 0, stream>>>(qs, hsv, kv, srcs, dists, We + l * HID,
            row_ptr, counts, lng + l * HID, lnb + l * HID, hb, NN);
    }
    k_final<<<(NN + 3) / 4, 256, 0, stream>>>(hb, Waf, baf, out, NN);
}

// Round 3
// 535.836 us; speedup vs baseline: 1.5153x; 1.1223x over previous
//
#include <hip/hip_runtime.h>
#include <cstdint>
#include <cstddef>

#define NN 50000
#define NE 600000
#define FIN 64
#define HID 128
#define NCLS 10
#define NLAYER 3

typedef __bf16 bf16x8 __attribute__((ext_vector_type(8)));
typedef float f32x4 __attribute__((ext_vector_type(4)));

__device__ __forceinline__ unsigned short f2bf(float f) {
    unsigned int u = __builtin_bit_cast(unsigned int, f);
    u += 0x7fffu + ((u >> 16) & 1u);
    return (unsigned short)(u >> 16);
}
__device__ __forceinline__ float bf2f(unsigned short s) {
    unsigned int u = ((unsigned int)s) << 16;
    return __builtin_bit_cast(float, u);
}

// ---------------------------------------------------------------- CSR build
__global__ __launch_bounds__(256) void k_count(const int* __restrict__ edst,
                                               int* __restrict__ counts) {
    int e = blockIdx.x * 256 + threadIdx.x;
    if (e < NE) atomicAdd(&counts[edst[e]], 1);
}

__global__ __launch_bounds__(512) void k_scan1(const int* __restrict__ counts,
                                               int* __restrict__ row_ptr,
                                               int* __restrict__ partials, int n) {
    __shared__ int sm[512];
    int tid = threadIdx.x;
    int i = blockIdx.x * 512 + tid;
    int v = (i < n) ? counts[i] : 0;
    sm[tid] = v;
    __syncthreads();
    #pragma unroll
    for (int off = 1; off < 512; off <<= 1) {
        int t = (tid >= off) ? sm[tid - off] : 0;
        __syncthreads();
        sm[tid] += t;
        __syncthreads();
    }
    if (i < n) row_ptr[i] = sm[tid] - v;
    if (tid == 511) partials[blockIdx.x] = sm[511];
}

__global__ __launch_bounds__(128) void k_scan2(int* __restrict__ partials, int nb) {
    __shared__ int sm[128];
    int t = threadIdx.x;
    int v = (t < nb) ? partials[t] : 0;
    sm[t] = v;
    __syncthreads();
    #pragma unroll
    for (int off = 1; off < 128; off <<= 1) {
        int x = (t >= off) ? sm[t - off] : 0;
        __syncthreads();
        sm[t] += x;
        __syncthreads();
    }
    if (t < nb) partials[t] = sm[t] - v;   // exclusive
}

__global__ __launch_bounds__(512) void k_scan3(int* __restrict__ row_ptr,
                                               const int* __restrict__ partials, int n) {
    int i = blockIdx.x * 512 + threadIdx.x;
    if (i < n) row_ptr[i] += partials[blockIdx.x];
}

__global__ __launch_bounds__(256) void k_fill(const int* __restrict__ esrc,
                                              const int* __restrict__ edst,
                                              const float* __restrict__ dist,
                                              int* __restrict__ cursor,
                                              const int* __restrict__ row_ptr,
                                              int2* __restrict__ srcd) {
    int e = blockIdx.x * 256 + threadIdx.x;
    if (e < NE) {
        int d = edst[e];
        int pos = atomicAdd(&cursor[d], 1);
        srcd[row_ptr[d] + pos] = make_int2(esrc[e], __float_as_int(dist[e]));
    }
}

// ---------------------------------------------------------------- converts
__global__ __launch_bounds__(256) void k_cvt(const float* __restrict__ in,
                                             unsigned short* __restrict__ out, int n4) {
    int i = blockIdx.x * 256 + threadIdx.x;
    if (i < n4) {
        float4 v = *(const float4*)(in + (size_t)i * 4);
        ushort4 o;
        o.x = f2bf(v.x); o.y = f2bf(v.y); o.z = f2bf(v.z); o.w = f2bf(v.w);
        *(ushort4*)(out + (size_t)i * 4) = o;
    }
}

// transpose 12 layer weight mats [128][128] f32 -> bf16 [col][k]
__global__ __launch_bounds__(256) void k_tw12(const float* __restrict__ Wq,
                                              const float* __restrict__ Wk,
                                              const float* __restrict__ Wv,
                                              const float* __restrict__ Ws,
                                              unsigned short* __restrict__ Wt) {
    int m = blockIdx.x >> 6;            // 0..11
    int l = m >> 2, which = m & 3;
    const float* src;
    if (which == 0) src = Wq; else if (which == 1) src = Wk;
    else if (which == 2) src = Wv; else src = Ws;
    src += (size_t)l * HID * HID;
    int idx = (blockIdx.x & 63) * 256 + threadIdx.x;   // 0..16383
    int c = idx >> 7, k = idx & 127;
    // store order: [l][q,k,v,s] contiguous
    Wt[(size_t)(l * 4 + which) * 16384 + (size_t)c * 128 + k] = f2bf(src[(size_t)k * 128 + c]);
}

// transpose W_before [64][128] f32 -> bf16 [128][64]
__global__ __launch_bounds__(256) void k_twb(const float* __restrict__ W,
                                             unsigned short* __restrict__ Wt) {
    int idx = blockIdx.x * 256 + threadIdx.x;   // 0..8191
    int c = idx >> 6, k = idx & 63;
    Wt[(size_t)c * 64 + k] = f2bf(W[(size_t)k * 128 + c]);
}

// ---------------------------------------------------------------- fused QKVS GEMM (LDS-free)
// A bf16 [nrows][128]; Wt bf16 [4][128col][128k]. Writes:
//   qb bf16 [r][128]  = (A@Wq + bq) * 0.25
//   kvb bf16 [r][256] interleaved {k[j], v[j]} pairs
//   hs f32 [r][128]   = A@Ws + bs
__global__ __launch_bounds__(256) void k_qkvs(
    const unsigned short* __restrict__ Ab, int nrows,
    const unsigned short* __restrict__ Wt,
    const float* __restrict__ bq, const float* __restrict__ bk,
    const float* __restrict__ bv, const float* __restrict__ bs,
    unsigned short* __restrict__ qb,
    unsigned short* __restrict__ kvb,
    float* __restrict__ hs)
{
    __shared__ float bsm[512];
    const int tid = threadIdx.x;
    #pragma unroll
    for (int i = tid; i < 512; i += 256) {
        const float* src = (i < 128) ? bq : (i < 256) ? bk : (i < 384) ? bv : bs;
        bsm[i] = src[i & 127];
    }
    __syncthreads();

    const int w = tid >> 6, lane = tid & 63;
    const int row0 = blockIdx.x * 64 + w * 16;
    const int arow = row0 + (lane & 15);
    const int ke = (lane >> 4) * 8;
    const bool rv = arow < nrows;

    bf16x8 z = {};
    bf16x8 a[4];
    #pragma unroll
    for (int kb = 0; kb < 4; ++kb)
        a[kb] = rv ? *(const bf16x8*)(Ab + (size_t)arow * 128 + kb * 32 + ke) : z;

    const int cbase = (lane >> 4) * 4;
    #pragma unroll
    for (int ct = 0; ct < 8; ++ct) {
        const int bcol = ct * 16 + (lane & 15);
        f32x4 aq = {0.f, 0.f, 0.f, 0.f};
        f32x4 ak = aq, av = aq, as = aq;
        #pragma unroll
        for (int kb = 0; kb < 4; ++kb) {
            const size_t bo = (size_t)bcol * 128 + kb * 32 + ke;
            bf16x8 b0 = *(const bf16x8*)(Wt + bo);
            bf16x8 b1 = *(const bf16x8*)(Wt + 16384 + bo);
            bf16x8 b2 = *(const bf16x8*)(Wt + 32768 + bo);
            bf16x8 b3 = *(const bf16x8*)(Wt + 49152 + bo);
            aq = __builtin_amdgcn_mfma_f32_16x16x32_bf16(a[kb], b0, aq, 0, 0, 0);
            ak = __builtin_amdgcn_mfma_f32_16x16x32_bf16(a[kb], b1, ak, 0, 0, 0);
            av = __builtin_amdgcn_mfma_f32_16x16x32_bf16(a[kb], b2, av, 0, 0, 0);
            as = __builtin_amdgcn_mfma_f32_16x16x32_bf16(a[kb], b3, as, 0, 0, 0);
        }
        const float biasq = bsm[bcol], biask = bsm[128 + bcol];
        const float biasv = bsm[256 + bcol], biass = bsm[384 + bcol];
        #pragma unroll
        for (int i = 0; i < 4; ++i) {
            int r = row0 + cbase + i;
            if (r >= nrows) continue;
            qb[(size_t)r * 128 + bcol] = f2bf((aq[i] + biasq) * 0.25f);
            ushort2 kvp;
            kvp.x = f2bf(ak[i] + biask);
            kvp.y = f2bf(av[i] + biasv);
            *(ushort2*)(kvb + (size_t)r * 256 + bcol * 2) = kvp;
            hs[(size_t)r * 128 + bcol] = as[i] + biass;
        }
    }
}

// ---------------------------------------------------------------- fc_before GEMM (LDS-free)
__global__ __launch_bounds__(256) void k_gin(
    const unsigned short* __restrict__ Ab, int nrows,
    const unsigned short* __restrict__ Wt,   // [128col][64k]
    const float* __restrict__ bias,
    unsigned short* __restrict__ hb)
{
    const int tid = threadIdx.x;
    const int w = tid >> 6, lane = tid & 63;
    const int row0 = blockIdx.x * 64 + w * 16;
    const int arow = row0 + (lane & 15);
    const int ke = (lane >> 4) * 8;
    const bool rv = arow < nrows;

    bf16x8 z = {};
    bf16x8 a[2];
    #pragma unroll
    for (int kb = 0; kb < 2; ++kb)
        a[kb] = rv ? *(const bf16x8*)(Ab + (size_t)arow * 64 + kb * 32 + ke) : z;

    const int cbase = (lane >> 4) * 4;
    #pragma unroll
    for (int ct = 0; ct < 8; ++ct) {
        const int bcol = ct * 16 + (lane & 15);
        f32x4 acc = {0.f, 0.f, 0.f, 0.f};
        #pragma unroll
        for (int kb = 0; kb < 2; ++kb) {
            bf16x8 b = *(const bf16x8*)(Wt + (size_t)bcol * 64 + kb * 32 + ke);
            acc = __builtin_amdgcn_mfma_f32_16x16x32_bf16(a[kb], b, acc, 0, 0, 0);
        }
        const float bv_ = bias[bcol];
        #pragma unroll
        for (int i = 0; i < 4; ++i) {
            int r = row0 + cbase + i;
            if (r >= nrows) continue;
            hb[(size_t)r * 128 + bcol] = f2bf(fmaxf(acc[i] + bv_, 0.f));
        }
    }
}

// ---------------------------------------------------------------- fused attention
// Fixed-shift softmax (scores are O(6) at most; exp(p) safe in fp32).
__global__ __launch_bounds__(256) void k_attn(
    const unsigned short* __restrict__ qb,
    const float* __restrict__ hs,
    const unsigned short* __restrict__ kvb,
    const int2* __restrict__ srcd,
    const float* __restrict__ We,
    const int* __restrict__ row_ptr,
    const float* __restrict__ lng,
    const float* __restrict__ lnb,
    unsigned short* __restrict__ hb, int nnodes)
{
    const int wid = threadIdx.x >> 6;
    const int lane = threadIdx.x & 63;
    const int n = blockIdx.x * 4 + wid;
    if (n >= nnodes) return;
    const int c0 = lane * 2;

    ushort2 qu = *(const ushort2*)(qb + (size_t)n * 128 + c0);
    const float q0 = bf2f(qu.x), q1 = bf2f(qu.y);
    const float2 hsv = *(const float2*)(hs + (size_t)n * 128 + c0);
    const float we0 = We[c0], we1 = We[c0 + 1];

    const int beg = row_ptr[n];
    const int cnt = row_ptr[n + 1] - beg;
    float s = 0.f, a0 = 0.f, a1 = 0.f;

    for (int base = 0; base < cnt; base += 64) {
        const int nb = min(64, cnt - base);
        int2 sd = make_int2(0, 0);
        if (lane < nb) sd = srcd[beg + base + lane];
        for (int i = 0; i < nb; i += 8) {
            const int m = min(8, nb - i);
            ushort4 u[8];
            float dd[8];
            #pragma unroll
            for (int j = 0; j < 8; ++j) {
                if (j < m) {
                    int sj = __shfl(sd.x, i + j);
                    dd[j] = __int_as_float(__shfl(sd.y, i + j));
                    u[j] = *(const ushort4*)(kvb + (size_t)sj * 256 + lane * 4);
                }
            }
            #pragma unroll
            for (int j = 0; j < 8; ++j) {
                if (j < m) {
                    float e0 = dd[j] * we0, e1 = dd[j] * we1;
                    float k0 = bf2f(u[j].x) + e0, k1 = bf2f(u[j].z) + e1;
                    float p = fmaf(q0, k0, q1 * k1);
                    p += __shfl_xor(p, 1);
                    p += __shfl_xor(p, 2);
                    p += __shfl_xor(p, 4);
                    float wgt = __expf(p);
                    s += wgt;
                    a0 = fmaf(bf2f(u[j].y) + e0, wgt, a0);
                    a1 = fmaf(bf2f(u[j].w) + e1, wgt, a1);
                }
            }
        }
    }
    float inv = 1.f / (s + 1e-16f);
    float o0 = fmaf(a0, inv, hsv.x);
    float o1 = fmaf(a1, inv, hsv.y);

    // LayerNorm over 128 features + ReLU -> bf16
    float t = o0 + o1;
    #pragma unroll
    for (int off = 1; off < 64; off <<= 1) t += __shfl_xor(t, off);
    float mean = t * 0.0078125f;
    float d0 = o0 - mean, d1 = o1 - mean;
    float vv = d0 * d0 + d1 * d1;
    #pragma unroll
    for (int off = 1; off < 64; off <<= 1) vv += __shfl_xor(vv, off);
    float rstd = rsqrtf(vv * 0.0078125f + 1e-5f);
    float y0 = fmaxf(d0 * rstd * lng[c0] + lnb[c0], 0.f);
    float y1 = fmaxf(d1 * rstd * lng[c0 + 1] + lnb[c0 + 1], 0.f);
    ushort2 o;
    o.x = f2bf(y0);
    o.y = f2bf(y1);
    *(ushort2*)(hb + (size_t)n * 128 + c0) = o;
}

// ---------------------------------------------------------------- fc_after + log_softmax
__global__ __launch_bounds__(256) void k_final(
    const unsigned short* __restrict__ hb,
    const float* __restrict__ Wa,      // [128][10]
    const float* __restrict__ ba,
    float* __restrict__ out, int nnodes)
{
    const int wid = threadIdx.x >> 6;
    const int lane = threadIdx.x & 63;
    const int n = blockIdx.x * 4 + wid;
    if (n >= nnodes) return;
    const int c0 = lane * 2;
    const float h0 = bf2f(hb[(size_t)n * 128 + c0]);
    const float h1 = bf2f(hb[(size_t)n * 128 + c0 + 1]);
    float logit[NCLS];
    #pragma unroll
    for (int c = 0; c < NCLS; ++c) {
        float p = h0 * Wa[c0 * NCLS + c] + h1 * Wa[(c0 + 1) * NCLS + c];
        #pragma unroll
        for (int off = 1; off < 64; off <<= 1) p += __shfl_xor(p, off);
        logit[c] = p + ba[c];
    }
    float mx = logit[0];
    #pragma unroll
    for (int c = 1; c < NCLS; ++c) mx = fmaxf(mx, logit[c]);
    float sum = 0.f;
    #pragma unroll
    for (int c = 0; c < NCLS; ++c) sum += __expf(logit[c] - mx);
    float lse = mx + __logf(sum);
    if (lane == 0) {
        #pragma unroll
        for (int c = 0; c < NCLS; ++c) out[(size_t)n * NCLS + c] = logit[c] - lse;
    }
}

// ---------------------------------------------------------------- launch
extern "C" void kernel_launch(void* const* d_in, const int* in_sizes, int n_in,
                              void* d_out, int out_size, void* d_ws, size_t ws_size,
                              hipStream_t stream)
{
    const float* x    = (const float*)d_in[0];
    const int*   ei   = (const int*)d_in[1];
    const float* dist = (const float*)d_in[2];
    const float* Wq   = (const float*)d_in[3];
    const float* bq   = (const float*)d_in[4];
    const float* Wk   = (const float*)d_in[5];
    const float* bk   = (const float*)d_in[6];
    const float* Wv   = (const float*)d_in[7];
    const float* bv   = (const float*)d_in[8];
    const float* We   = (const float*)d_in[9];
    const float* Wsk  = (const float*)d_in[10];
    const float* bs   = (const float*)d_in[11];
    const float* lng  = (const float*)d_in[12];
    const float* lnb  = (const float*)d_in[13];
    const float* Wbe  = (const float*)d_in[14];
    const float* bbe  = (const float*)d_in[15];
    const float* Waf  = (const float*)d_in[16];
    const float* baf  = (const float*)d_in[17];
    float* out = (float*)d_out;
    const int* esrc = ei;
    const int* edst = ei + NE;

    char* ws = (char*)d_ws;
    size_t off = 0;
    unsigned short* qb = (unsigned short*)(ws + off);   off += 12800000;
    float* hs          = (float*)(ws + off);            off += 25600000;
    unsigned short* kvb = (unsigned short*)(ws + off);  off += 25600000;
    unsigned short* hb = (unsigned short*)(ws + off);   off += 12800000;
    unsigned short* xb = (unsigned short*)(ws + off);   off += 6400000;
    unsigned short* Wt12 = (unsigned short*)(ws + off); off += 393216;
    unsigned short* Wbt = (unsigned short*)(ws + off);  off += 16384;
    int* counts   = (int*)(ws + off);  off += 200192;
    int* cursor   = (int*)(ws + off);  off += 200192;
    int* row_ptr  = (int*)(ws + off);  off += 200192;
    int* partials = (int*)(ws + off);  off += 512;
    int2* srcd    = (int2*)(ws + off); off += (size_t)NE * 8;

    // CSR build (row_ptr has NN+1 entries)
    hipMemsetAsync(counts, 0, (NN + 1) * sizeof(int), stream);
    hipMemsetAsync(cursor, 0, NN * sizeof(int), stream);
    k_count<<<(NE + 255) / 256, 256, 0, stream>>>(edst, counts);
    int nsb = (NN + 1 + 511) / 512;   // 98
    k_scan1<<<nsb, 512, 0, stream>>>(counts, row_ptr, partials, NN + 1);
    k_scan2<<<1, 128, 0, stream>>>(partials, nsb);
    k_scan3<<<nsb, 512, 0, stream>>>(row_ptr, partials, NN + 1);
    k_fill<<<(NE + 255) / 256, 256, 0, stream>>>(esrc, edst, dist, cursor, row_ptr, srcd);

    // converts
    k_cvt<<<(NN * FIN / 4 + 255) / 256, 256, 0, stream>>>(x, xb, NN * FIN / 4);
    k_tw12<<<12 * 64, 256, 0, stream>>>(Wq, Wk, Wv, Wsk, Wt12);
    k_twb<<<32, 256, 0, stream>>>(Wbe, Wbt);

    const int ngb = (NN + 63) / 64;   // 782

    // h = relu(x @ W_before + b_before)  -> hb (bf16)
    k_gin<<<ngb, 256, 0, stream>>>(xb, NN, Wbt, bbe, hb);

    for (int l = 0; l < NLAYER; ++l) {
        const unsigned short* wt = Wt12 + (size_t)l * 4 * 16384;
        k_qkvs<<<ngb, 256, 0, stream>>>(hb, NN, wt,
            bq + l * HID, bk + l * HID, bv + l * HID, bs + l * HID,
            qb, kvb, hs);
        k_attn<<<(NN + 3) / 4, 256, 0, stream>>>(qb, hs, kvb, srcd, We + l * HID,
            row_ptr, lng + l * HID, lnb + l * HID, hb, NN);
    }
    k_final<<<(NN + 3) / 4, 256, 0, stream>>>(hb, Waf, baf, out, NN);
}

// Round 4
// 443.785 us; speedup vs baseline: 1.8296x; 1.2074x over previous
//
#include <hip/hip_runtime.h>
#include <cstdint>
#include <cstddef>

#define NN 50000
#define NE 600000
#define FIN 64
#define HID 128
#define NCLS 10
#define NLAYER 3

// 0.25 (1/sqrt(16)) * log2(e)  -> softmax exp becomes a single exp2
#define QSCALE 0.36067376022224085f

typedef __bf16 bf16x8 __attribute__((ext_vector_type(8)));
typedef float f32x4 __attribute__((ext_vector_type(4)));

__device__ __forceinline__ unsigned short f2bf(float f) {
    unsigned int u = __builtin_bit_cast(unsigned int, f);
    u += 0x7fffu + ((u >> 16) & 1u);
    return (unsigned short)(u >> 16);
}
__device__ __forceinline__ float bf2f(unsigned short s) {
    unsigned int u = ((unsigned int)s) << 16;
    return __builtin_bit_cast(float, u);
}
__device__ __forceinline__ float lo16f(unsigned int w) {
    return __builtin_bit_cast(float, w << 16);
}
__device__ __forceinline__ float hi16f(unsigned int w) {
    return __builtin_bit_cast(float, w & 0xffff0000u);
}

// ---------------------------------------------------------------- CSR build
__global__ __launch_bounds__(256) void k_count(const int* __restrict__ edst,
                                               int* __restrict__ counts) {
    int e = blockIdx.x * 256 + threadIdx.x;
    if (e < NE) atomicAdd(&counts[edst[e]], 1);
}

__global__ __launch_bounds__(512) void k_scan1(const int* __restrict__ counts,
                                               int* __restrict__ row_ptr,
                                               int* __restrict__ partials, int n) {
    __shared__ int sm[512];
    int tid = threadIdx.x;
    int i = blockIdx.x * 512 + tid;
    int v = (i < n) ? counts[i] : 0;
    sm[tid] = v;
    __syncthreads();
    #pragma unroll
    for (int off = 1; off < 512; off <<= 1) {
        int t = (tid >= off) ? sm[tid - off] : 0;
        __syncthreads();
        sm[tid] += t;
        __syncthreads();
    }
    if (i < n) row_ptr[i] = sm[tid] - v;
    if (tid == 511) partials[blockIdx.x] = sm[511];
}

__global__ __launch_bounds__(128) void k_scan2(int* __restrict__ partials, int nb) {
    __shared__ int sm[128];
    int t = threadIdx.x;
    int v = (t < nb) ? partials[t] : 0;
    sm[t] = v;
    __syncthreads();
    #pragma unroll
    for (int off = 1; off < 128; off <<= 1) {
        int x = (t >= off) ? sm[t - off] : 0;
        __syncthreads();
        sm[t] += x;
        __syncthreads();
    }
    if (t < nb) partials[t] = sm[t] - v;   // exclusive
}

__global__ __launch_bounds__(512) void k_scan3(int* __restrict__ row_ptr,
                                               const int* __restrict__ partials, int n) {
    int i = blockIdx.x * 512 + threadIdx.x;
    if (i < n) row_ptr[i] += partials[blockIdx.x];
}

__global__ __launch_bounds__(256) void k_fill(const int* __restrict__ esrc,
                                              const int* __restrict__ edst,
                                              const float* __restrict__ dist,
                                              int* __restrict__ cursor,
                                              const int* __restrict__ row_ptr,
                                              int2* __restrict__ srcd) {
    int e = blockIdx.x * 256 + threadIdx.x;
    if (e < NE) {
        int d = edst[e];
        int pos = atomicAdd(&cursor[d], 1);
        srcd[row_ptr[d] + pos] = make_int2(esrc[e], __float_as_int(dist[e]));
    }
}

// ---------------------------------------------------------------- weight prep
// transpose 12 layer weight mats [128][128] f32 -> bf16 [l][{q,k,v,s}][col][k]
__global__ __launch_bounds__(256) void k_tw12(const float* __restrict__ Wq,
                                              const float* __restrict__ Wk,
                                              const float* __restrict__ Wv,
                                              const float* __restrict__ Ws,
                                              unsigned short* __restrict__ Wt) {
    int m = blockIdx.x >> 6;            // 0..11
    int l = m >> 2, which = m & 3;
    const float* src;
    if (which == 0) src = Wq; else if (which == 1) src = Wk;
    else if (which == 2) src = Wv; else src = Ws;
    src += (size_t)l * HID * HID;
    int idx = (blockIdx.x & 63) * 256 + threadIdx.x;   // 0..16383
    int c = idx >> 7, k = idx & 127;
    Wt[(size_t)(l * 4 + which) * 16384 + (size_t)c * 128 + k] = f2bf(src[(size_t)k * 128 + c]);
}

// transpose W_before [64][128] f32 -> bf16 [128][64]
__global__ __launch_bounds__(256) void k_twb(const float* __restrict__ W,
                                             unsigned short* __restrict__ Wt) {
    int idx = blockIdx.x * 256 + threadIdx.x;   // 0..8191
    int c = idx >> 6, k = idx & 63;
    Wt[(size_t)c * 64 + k] = f2bf(W[(size_t)k * 128 + c]);
}

// transpose W_after [128][10] f32 -> f32 [10][128]
__global__ __launch_bounds__(256) void k_twa(const float* __restrict__ W,
                                             float* __restrict__ Wt) {
    int i = blockIdx.x * 256 + threadIdx.x;   // 0..1279
    if (i < 1280) {
        int c = i >> 7, f = i & 127;
        Wt[i] = W[f * 10 + c];
    }
}

// ---------------------------------------------------------------- fused QKVS GEMM
// 8 waves; wave w: matrix m=w>>1 (q,k,v,s), column-half ch=w&1.
// B (half-matrix) held entirely in registers; loaded once per block.
__global__ __launch_bounds__(512) void k_qkvs(
    const unsigned short* __restrict__ Ab, int nrows,
    const unsigned short* __restrict__ Wt,   // [4][128col][128k]
    const float* __restrict__ bq, const float* __restrict__ bk,
    const float* __restrict__ bv, const float* __restrict__ bs,
    unsigned short* __restrict__ qb,
    unsigned short* __restrict__ kvb,        // [node][k0..127 | v0..127]
    unsigned short* __restrict__ hsb)
{
    const int tid = threadIdx.x;
    const int w = tid >> 6, lane = tid & 63;
    const int m = w >> 1, ch = w & 1;
    const float* bias = (m == 0) ? bq : (m == 1) ? bk : (m == 2) ? bv : bs;
    const unsigned short* Wm = Wt + (size_t)m * 16384;
    const int lc = lane & 15, lk = lane >> 4;

    bf16x8 b[4][4];
    float bb[4];
    #pragma unroll
    for (int ct = 0; ct < 4; ++ct) {
        int col = ch * 64 + ct * 16 + lc;
        bb[ct] = bias[col];
        #pragma unroll
        for (int kb = 0; kb < 4; ++kb)
            b[ct][kb] = *(const bf16x8*)(Wm + (size_t)col * 128 + kb * 32 + lk * 8);
    }

    const int r0 = blockIdx.x * 64;
    #pragma unroll
    for (int rt = 0; rt < 4; ++rt) {
        const int arow = r0 + rt * 16 + lc;
        bf16x8 z = {};
        bf16x8 a[4];
        #pragma unroll
        for (int kb = 0; kb < 4; ++kb)
            a[kb] = (arow < nrows) ? *(const bf16x8*)(Ab + (size_t)arow * 128 + kb * 32 + lk * 8) : z;
        #pragma unroll
        for (int ct = 0; ct < 4; ++ct) {
            f32x4 acc = {0.f, 0.f, 0.f, 0.f};
            #pragma unroll
            for (int kb = 0; kb < 4; ++kb)
                acc = __builtin_amdgcn_mfma_f32_16x16x32_bf16(a[kb], b[ct][kb], acc, 0, 0, 0);
            const int col = ch * 64 + ct * 16 + lc;
            #pragma unroll
            for (int i = 0; i < 4; ++i) {
                int r = r0 + rt * 16 + lk * 4 + i;
                if (r >= nrows) continue;
                float val = acc[i] + bb[ct];
                if (m == 0)      qb[(size_t)r * 128 + col] = f2bf(val * QSCALE);
                else if (m == 1) kvb[(size_t)r * 256 + col] = f2bf(val);
                else if (m == 2) kvb[(size_t)r * 256 + 128 + col] = f2bf(val);
                else             hsb[(size_t)r * 128 + col] = f2bf(val);
            }
        }
    }
}

// ---------------------------------------------------------------- fc_before GEMM
__global__ __launch_bounds__(256) void k_gin(
    const float* __restrict__ x, int nrows,
    const unsigned short* __restrict__ Wt,   // [128col][64k]
    const float* __restrict__ bias,
    unsigned short* __restrict__ hb)
{
    const int tid = threadIdx.x;
    const int w = tid >> 6, lane = tid & 63;
    const int row0 = blockIdx.x * 64 + w * 16;
    const int lc = lane & 15, lk = lane >> 4;
    const int arow = row0 + lc;
    const bool rv = arow < nrows;

    bf16x8 a[2];
    #pragma unroll
    for (int kb = 0; kb < 2; ++kb) {
        union { bf16x8 v; unsigned short u[8]; } t;
        #pragma unroll
        for (int q = 0; q < 2; ++q) {
            float4 f = rv ? *(const float4*)(x + (size_t)arow * 64 + kb * 32 + lk * 8 + q * 4)
                          : make_float4(0.f, 0.f, 0.f, 0.f);
            t.u[q * 4 + 0] = f2bf(f.x); t.u[q * 4 + 1] = f2bf(f.y);
            t.u[q * 4 + 2] = f2bf(f.z); t.u[q * 4 + 3] = f2bf(f.w);
        }
        a[kb] = t.v;
    }

    const int cbase = lk * 4;
    #pragma unroll
    for (int ct = 0; ct < 8; ++ct) {
        const int bcol = ct * 16 + lc;
        f32x4 acc = {0.f, 0.f, 0.f, 0.f};
        #pragma unroll
        for (int kb = 0; kb < 2; ++kb) {
            bf16x8 b = *(const bf16x8*)(Wt + (size_t)bcol * 64 + kb * 32 + lk * 8);
            acc = __builtin_amdgcn_mfma_f32_16x16x32_bf16(a[kb], b, acc, 0, 0, 0);
        }
        const float bv_ = bias[bcol];
        #pragma unroll
        for (int i = 0; i < 4; ++i) {
            int r = row0 + cbase + i;
            if (r >= nrows) continue;
            hb[(size_t)r * 128 + bcol] = f2bf(fmaxf(acc[i] + bv_, 0.f));
        }
    }
}

// ---------------------------------------------------------------- fused attention
// One wave per dst node. Lane = (head h = lane>>3) x (edge slot j = lane&7).
// Full 16-dim per-head dot in-register; fixed-shift softmax in exp2 domain
// (q pre-scaled by 0.25*log2e). Edge-embedding factored:
//   p = q.k + dist*qwe ;  out_v = sum(w*v) + we*sum(w*dist).
#define LOADB(bi, kw, vw, dd, vv) {                                           \
    int rel_ = (bi) * 8 + j;                                                  \
    vv = rel_ < cnt;                                                          \
    int2 e2_ = srcd[beg + (vv ? rel_ : 0)];                                   \
    dd = __int_as_float(e2_.y);                                               \
    const unsigned short* kr_ = kvb + (size_t)e2_.x * 256 + h * 16;           \
    *(uint4*)(kw)       = *(const uint4*)(kr_);                               \
    *(uint4*)((kw) + 4) = *(const uint4*)(kr_ + 8);                           \
    *(uint4*)(vw)       = *(const uint4*)(kr_ + 128);                         \
    *(uint4*)((vw) + 4) = *(const uint4*)(kr_ + 136); }

#define COMPB(kw, vw, dd, vv) {                                               \
    float p_ = 0.f;                                                           \
    _Pragma("unroll")                                                         \
    for (int d2 = 0; d2 < 8; ++d2) {                                          \
        p_ = fmaf(qf[2 * d2],     lo16f((kw)[d2]), p_);                       \
        p_ = fmaf(qf[2 * d2 + 1], hi16f((kw)[d2]), p_);                       \
    }                                                                         \
    p_ = fmaf(dd, qwe, p_);                                                   \
    float wgt_ = exp2f(p_);                                                   \
    wgt_ = (vv) ? wgt_ : 0.f;                                                 \
    s += wgt_;                                                                \
    sd = fmaf(dd, wgt_, sd);                                                  \
    _Pragma("unroll")                                                         \
    for (int d2 = 0; d2 < 8; ++d2) {                                          \
        vacc[2 * d2]     = fmaf(lo16f((vw)[d2]), wgt_, vacc[2 * d2]);         \
        vacc[2 * d2 + 1] = fmaf(hi16f((vw)[d2]), wgt_, vacc[2 * d2 + 1]);     \
    } }

template <int LAST>
__global__ __launch_bounds__(256) void k_attn(
    const unsigned short* __restrict__ qb,
    const unsigned short* __restrict__ hsb,
    const unsigned short* __restrict__ kvb,
    const int2* __restrict__ srcd,
    const float* __restrict__ We,
    const int* __restrict__ row_ptr,
    const float* __restrict__ lng,
    const float* __restrict__ lnb,
    unsigned short* __restrict__ hb,
    const float* __restrict__ Wat,     // [10][128] (LAST)
    const float* __restrict__ ba,      // [10]      (LAST)
    float* __restrict__ out, int nnodes)
{
    const int wid = threadIdx.x >> 6;
    const int lane = threadIdx.x & 63;
    const int n = blockIdx.x * 4 + wid;
    if (n >= nnodes) return;
    const int h = lane >> 3, j = lane & 7;
    const int c0 = lane * 2;

    // per-head scaled q (16 dims) in registers
    unsigned int uq[8];
    *(uint4*)(uq)     = *(const uint4*)(qb + (size_t)n * 128 + h * 16);
    *(uint4*)(uq + 4) = *(const uint4*)(qb + (size_t)n * 128 + h * 16 + 8);
    float qf[16];
    #pragma unroll
    for (int d = 0; d < 8; ++d) {
        qf[2 * d]     = lo16f(uq[d]);
        qf[2 * d + 1] = hi16f(uq[d]);
    }
    // qwe = q_scaled . we_head  (compile-time indices only)
    float qwe = 0.f;
    #pragma unroll
    for (int d4 = 0; d4 < 4; ++d4) {
        float4 wv = *(const float4*)(We + h * 16 + d4 * 4);
        qwe = fmaf(qf[d4 * 4 + 0], wv.x, qwe);
        qwe = fmaf(qf[d4 * 4 + 1], wv.y, qwe);
        qwe = fmaf(qf[d4 * 4 + 2], wv.z, qwe);
        qwe = fmaf(qf[d4 * 4 + 3], wv.w, qwe);
    }

    const int beg = row_ptr[n];
    const int cnt = row_ptr[n + 1] - beg;
    float s = 0.f, sd = 0.f;
    float vacc[16];
    #pragma unroll
    for (int d = 0; d < 16; ++d) vacc[d] = 0.f;

    if (cnt > 0) {
        const int nbatch = (cnt + 7) >> 3;
        unsigned int kwA[8], vwA[8], kwB[8], vwB[8];
        float dA, dB; bool vA, vB;
        LOADB(0, kwA, vwA, dA, vA);
        int b = 0;
        while (true) {
            if (b + 1 < nbatch) LOADB(b + 1, kwB, vwB, dB, vB);
            COMPB(kwA, vwA, dA, vA);
            ++b;
            if (b >= nbatch) break;
            if (b + 1 < nbatch) LOADB(b + 1, kwA, vwA, dA, vA);
            COMPB(kwB, vwB, dB, vB);
            ++b;
            if (b >= nbatch) break;
        }
    }

    // reduce s, sd across the 8 slots of this head
    #pragma unroll
    for (int msk = 1; msk < 8; msk <<= 1) {
        s  += __shfl_xor(s, msk);
        sd += __shfl_xor(sd, msk);
    }
    // transpose-reduce vacc: lane (h,j) ends with dims {2j, 2j+1} of head h
    const bool b4 = (lane & 4) != 0;
    float c8[8];
    #pragma unroll
    for (int i = 0; i < 8; ++i) {
        float sendv = b4 ? vacc[i] : vacc[8 + i];
        float keep  = b4 ? vacc[8 + i] : vacc[i];
        c8[i] = keep + __shfl_xor(sendv, 4);
    }
    const bool b2 = (lane & 2) != 0;
    float c4[4];
    #pragma unroll
    for (int i = 0; i < 4; ++i) {
        float sendv = b2 ? c8[i] : c8[4 + i];
        float keep  = b2 ? c8[4 + i] : c8[i];
        c4[i] = keep + __shfl_xor(sendv, 2);
    }
    const bool b1 = (lane & 1) != 0;
    float c2[2];
    #pragma unroll
    for (int i = 0; i < 2; ++i) {
        float sendv = b1 ? c4[i] : c4[2 + i];
        float keep  = b1 ? c4[2 + i] : c4[i];
        c2[i] = keep + __shfl_xor(sendv, 1);
    }

    const float inv = 1.f / (s + 1e-16f);
    const float we0 = We[c0], we1 = We[c0 + 1];
    const ushort2 hu = *(const ushort2*)(hsb + (size_t)n * 128 + c0);
    float o0 = fmaf(fmaf(we0, sd, c2[0]), inv, bf2f(hu.x));
    float o1 = fmaf(fmaf(we1, sd, c2[1]), inv, bf2f(hu.y));

    // LayerNorm over 128 features + ReLU
    float t = o0 + o1;
    #pragma unroll
    for (int off = 1; off < 64; off <<= 1) t += __shfl_xor(t, off);
    float mean = t * 0.0078125f;
    float d0 = o0 - mean, d1 = o1 - mean;
    float vv2 = d0 * d0 + d1 * d1;
    #pragma unroll
    for (int off = 1; off < 64; off <<= 1) vv2 += __shfl_xor(vv2, off);
    float rstd = rsqrtf(vv2 * 0.0078125f + 1e-5f);
    float y0 = fmaxf(d0 * rstd * lng[c0] + lnb[c0], 0.f);
    float y1 = fmaxf(d1 * rstd * lng[c0 + 1] + lnb[c0 + 1], 0.f);

    if (LAST) {
        // fused fc_after + log_softmax
        float lg[NCLS];
        #pragma unroll
        for (int c = 0; c < NCLS; ++c) {
            float2 wv = *(const float2*)(Wat + c * 128 + c0);
            float p = fmaf(y0, wv.x, y1 * wv.y);
            #pragma unroll
            for (int msk = 1; msk < 64; msk <<= 1) p += __shfl_xor(p, msk);
            lg[c] = p + ba[c];
        }
        float mx = lg[0];
        #pragma unroll
        for (int c = 1; c < NCLS; ++c) mx = fmaxf(mx, lg[c]);
        float sum = 0.f;
        #pragma unroll
        for (int c = 0; c < NCLS; ++c) sum += __expf(lg[c] - mx);
        float lse = mx + __logf(sum);
        if (lane == 0) {
            #pragma unroll
            for (int c = 0; c < NCLS; ++c) out[(size_t)n * NCLS + c] = lg[c] - lse;
        }
    } else {
        ushort2 o;
        o.x = f2bf(y0);
        o.y = f2bf(y1);
        *(ushort2*)(hb + (size_t)n * 128 + c0) = o;
    }
}

// ---------------------------------------------------------------- launch
extern "C" void kernel_launch(void* const* d_in, const int* in_sizes, int n_in,
                              void* d_out, int out_size, void* d_ws, size_t ws_size,
                              hipStream_t stream)
{
    const float* x    = (const float*)d_in[0];
    const int*   ei   = (const int*)d_in[1];
    const float* dist = (const float*)d_in[2];
    const float* Wq   = (const float*)d_in[3];
    const float* bq   = (const float*)d_in[4];
    const float* Wk   = (const float*)d_in[5];
    const float* bk   = (const float*)d_in[6];
    const float* Wv   = (const float*)d_in[7];
    const float* bv   = (const float*)d_in[8];
    const float* We   = (const float*)d_in[9];
    const float* Wsk  = (const float*)d_in[10];
    const float* bs   = (const float*)d_in[11];
    const float* lng  = (const float*)d_in[12];
    const float* lnb  = (const float*)d_in[13];
    const float* Wbe  = (const float*)d_in[14];
    const float* bbe  = (const float*)d_in[15];
    const float* Waf  = (const float*)d_in[16];
    const float* baf  = (const float*)d_in[17];
    float* out = (float*)d_out;
    const int* esrc = ei;
    const int* edst = ei + NE;

    char* ws = (char*)d_ws;
    size_t off = 0;
    unsigned short* qb  = (unsigned short*)(ws + off); off += 12800000;
    unsigned short* hsb = (unsigned short*)(ws + off); off += 12800000;
    unsigned short* kvb = (unsigned short*)(ws + off); off += 25600000;
    unsigned short* hb  = (unsigned short*)(ws + off); off += 12800000;
    unsigned short* Wt12 = (unsigned short*)(ws + off); off += 393216;
    unsigned short* Wbt  = (unsigned short*)(ws + off); off += 16384;
    float* Wat = (float*)(ws + off);   off += 5120;
    int* counts   = (int*)(ws + off);  off += 200192;
    int* cursor   = (int*)(ws + off);  off += 200192;
    int* row_ptr  = (int*)(ws + off);  off += 200192;
    int* partials = (int*)(ws + off);  off += 512;
    int2* srcd    = (int2*)(ws + off); off += (size_t)NE * 8;

    // CSR build (row_ptr has NN+1 entries)
    hipMemsetAsync(counts, 0, (NN + 1) * sizeof(int), stream);
    hipMemsetAsync(cursor, 0, NN * sizeof(int), stream);
    k_count<<<(NE + 255) / 256, 256, 0, stream>>>(edst, counts);
    int nsb = (NN + 1 + 511) / 512;   // 98
    k_scan1<<<nsb, 512, 0, stream>>>(counts, row_ptr, partials, NN + 1);
    k_scan2<<<1, 128, 0, stream>>>(partials, nsb);
    k_scan3<<<nsb, 512, 0, stream>>>(row_ptr, partials, NN + 1);
    k_fill<<<(NE + 255) / 256, 256, 0, stream>>>(esrc, edst, dist, cursor, row_ptr, srcd);

    // weight prep
    k_tw12<<<12 * 64, 256, 0, stream>>>(Wq, Wk, Wv, Wsk, Wt12);
    k_twb<<<32, 256, 0, stream>>>(Wbe, Wbt);
    k_twa<<<5, 256, 0, stream>>>(Waf, Wat);

    const int ngb = (NN + 63) / 64;   // 782

    // h = relu(x @ W_before + b_before)  -> hb (bf16); converts f32 x inline
    k_gin<<<ngb, 256, 0, stream>>>(x, NN, Wbt, bbe, hb);

    for (int l = 0; l < NLAYER; ++l) {
        const unsigned short* wt = Wt12 + (size_t)l * 4 * 16384;
        k_qkvs<<<ngb, 512, 0, stream>>>(hb, NN, wt,
            bq + l * HID, bk + l * HID, bv + l * HID, bs + l * HID,
            qb, kvb, hsb);
        if (l < NLAYER - 1) {
            k_attn<0><<<(NN + 3) / 4, 256, 0, stream>>>(qb, hsb, kvb, srcd, We + l * HID,
                row_ptr, lng + l * HID, lnb + l * HID, hb, nullptr, nullptr, nullptr, NN);
        } else {
            k_attn<1><<<(NN + 3) / 4, 256, 0, stream>>>(qb, hsb, kvb, srcd, We + l * HID,
                row_ptr, lng + l * HID, lnb + l * HID, hb, Wat, baf, out, NN);
        }
    }
}

// Round 5
// 396.100 us; speedup vs baseline: 2.0498x; 1.1204x over previous
//
#include <hip/hip_runtime.h>
#include <cstdint>
#include <cstddef>

#define NN 50000
#define NE 600000
#define FIN 64
#define HID 128
#define NCLS 10
#define NLAYER 3

// 0.25 (1/sqrt(16)) * log2(e)  -> softmax exp becomes a single exp2
#define QSCALE 0.36067376022224085f

typedef __bf16 bf16x8 __attribute__((ext_vector_type(8)));
typedef float f32x4 __attribute__((ext_vector_type(4)));
typedef float f32x2 __attribute__((ext_vector_type(2)));

__device__ __forceinline__ unsigned short f2bf(float f) {
    unsigned int u = __builtin_bit_cast(unsigned int, f);
    u += 0x7fffu + ((u >> 16) & 1u);
    return (unsigned short)(u >> 16);
}
__device__ __forceinline__ float bf2f(unsigned short s) {
    unsigned int u = ((unsigned int)s) << 16;
    return __builtin_bit_cast(float, u);
}
__device__ __forceinline__ float lo16f(unsigned int w) {
    return __builtin_bit_cast(float, w << 16);
}
__device__ __forceinline__ float hi16f(unsigned int w) {
    return __builtin_bit_cast(float, w & 0xffff0000u);
}

// ---------------------------------------------------------------- CSR build
__global__ __launch_bounds__(256) void k_count(const int* __restrict__ edst,
                                               int* __restrict__ counts) {
    int e = blockIdx.x * 256 + threadIdx.x;
    if (e < NE) atomicAdd(&counts[edst[e]], 1);
}

__global__ __launch_bounds__(512) void k_scan1(const int* __restrict__ counts,
                                               int* __restrict__ row_ptr,
                                               int* __restrict__ partials, int n) {
    __shared__ int sm[512];
    int tid = threadIdx.x;
    int i = blockIdx.x * 512 + tid;
    int v = (i < n) ? counts[i] : 0;
    sm[tid] = v;
    __syncthreads();
    #pragma unroll
    for (int off = 1; off < 512; off <<= 1) {
        int t = (tid >= off) ? sm[tid - off] : 0;
        __syncthreads();
        sm[tid] += t;
        __syncthreads();
    }
    if (i < n) row_ptr[i] = sm[tid] - v;
    if (tid == 511) partials[blockIdx.x] = sm[511];
}

__global__ __launch_bounds__(128) void k_scan2(int* __restrict__ partials, int nb) {
    __shared__ int sm[128];
    int t = threadIdx.x;
    int v = (t < nb) ? partials[t] : 0;
    sm[t] = v;
    __syncthreads();
    #pragma unroll
    for (int off = 1; off < 128; off <<= 1) {
        int x = (t >= off) ? sm[t - off] : 0;
        __syncthreads();
        sm[t] += x;
        __syncthreads();
    }
    if (t < nb) partials[t] = sm[t] - v;   // exclusive
}

__global__ __launch_bounds__(512) void k_scan3(int* __restrict__ row_ptr,
                                               const int* __restrict__ partials, int n) {
    int i = blockIdx.x * 512 + threadIdx.x;
    if (i < n) row_ptr[i] += partials[blockIdx.x];
}

__global__ __launch_bounds__(256) void k_fill(const int* __restrict__ esrc,
                                              const int* __restrict__ edst,
                                              const float* __restrict__ dist,
                                              int* __restrict__ cursor,
                                              const int* __restrict__ row_ptr,
                                              int2* __restrict__ srcd) {
    int e = blockIdx.x * 256 + threadIdx.x;
    if (e < NE) {
        int d = edst[e];
        int pos = atomicAdd(&cursor[d], 1);
        srcd[row_ptr[d] + pos] = make_int2(esrc[e], __float_as_int(dist[e]));
    }
}

// ---------------------------------------------------------------- weight prep (merged)
// blocks 0..767: 12x [128][128] f32 -> bf16 [l][{q,k,v,s}][col][k]
// blocks 768..799: W_before [64][128] -> bf16 [128col][64k]
// blocks 800..804: W_after [128][10] -> f32 [10][128]
__global__ __launch_bounds__(256) void k_wprep(
    const float* __restrict__ Wq, const float* __restrict__ Wk,
    const float* __restrict__ Wv, const float* __restrict__ Ws,
    const float* __restrict__ Wbe, const float* __restrict__ Waf,
    unsigned short* __restrict__ Wt12,
    unsigned short* __restrict__ Wbt,
    float* __restrict__ Wat)
{
    int blk = blockIdx.x;
    int tid = threadIdx.x;
    if (blk < 768) {
        int m = blk >> 6;                 // 0..11
        int l = m >> 2, which = m & 3;
        const float* src;
        if (which == 0) src = Wq; else if (which == 1) src = Wk;
        else if (which == 2) src = Wv; else src = Ws;
        src += (size_t)l * HID * HID;
        int idx = (blk & 63) * 256 + tid; // 0..16383
        int c = idx >> 7, k = idx & 127;
        Wt12[(size_t)m * 16384 + (size_t)c * 128 + k] = f2bf(src[(size_t)k * 128 + c]);
    } else if (blk < 800) {
        int idx = (blk - 768) * 256 + tid;  // 0..8191
        int c = idx >> 6, k = idx & 63;
        Wbt[(size_t)c * 64 + k] = f2bf(Wbe[(size_t)k * 128 + c]);
    } else {
        int i = (blk - 800) * 256 + tid;    // 0..1279
        if (i < 1280) {
            int c = i >> 7, f = i & 127;
            Wat[i] = Waf[f * 10 + c];
        }
    }
}

// ---------------------------------------------------------------- fused QKVS GEMM
// 8 waves; wave w: matrix m=w>>1 (q,k,v,s), column-half ch=w&1.
// B (half-matrix) held entirely in registers; loaded once per block.
// k,v outputs stored fp8-e4m3 (kv8 row: [k 128B | v 128B]).
__global__ __launch_bounds__(512) void k_qkvs(
    const unsigned short* __restrict__ Ab, int nrows,
    const unsigned short* __restrict__ Wt,   // [4][128col][128k]
    const float* __restrict__ bq, const float* __restrict__ bk,
    const float* __restrict__ bv, const float* __restrict__ bs,
    unsigned short* __restrict__ qb,
    unsigned char* __restrict__ kv8,
    unsigned short* __restrict__ hsb)
{
    const int tid = threadIdx.x;
    const int w = tid >> 6, lane = tid & 63;
    const int m = w >> 1, ch = w & 1;
    const float* bias = (m == 0) ? bq : (m == 1) ? bk : (m == 2) ? bv : bs;
    const unsigned short* Wm = Wt + (size_t)m * 16384;
    const int lc = lane & 15, lk = lane >> 4;

    bf16x8 b[4][4];
    float bb[4];
    #pragma unroll
    for (int ct = 0; ct < 4; ++ct) {
        int col = ch * 64 + ct * 16 + lc;
        bb[ct] = bias[col];
        #pragma unroll
        for (int kb = 0; kb < 4; ++kb)
            b[ct][kb] = *(const bf16x8*)(Wm + (size_t)col * 128 + kb * 32 + lk * 8);
    }

    const int r0 = blockIdx.x * 64;
    #pragma unroll
    for (int rt = 0; rt < 4; ++rt) {
        const int arow = r0 + rt * 16 + lc;
        bf16x8 z = {};
        bf16x8 a[4];
        #pragma unroll
        for (int kb = 0; kb < 4; ++kb)
            a[kb] = (arow < nrows) ? *(const bf16x8*)(Ab + (size_t)arow * 128 + kb * 32 + lk * 8) : z;
        #pragma unroll
        for (int ct = 0; ct < 4; ++ct) {
            f32x4 acc = {0.f, 0.f, 0.f, 0.f};
            #pragma unroll
            for (int kb = 0; kb < 4; ++kb)
                acc = __builtin_amdgcn_mfma_f32_16x16x32_bf16(a[kb], b[ct][kb], acc, 0, 0, 0);
            const int col = ch * 64 + ct * 16 + lc;
            #pragma unroll
            for (int i = 0; i < 4; ++i) {
                int r = r0 + rt * 16 + lk * 4 + i;
                if (r >= nrows) continue;
                float val = acc[i] + bb[ct];
                if (m == 0) {
                    qb[(size_t)r * 128 + col] = f2bf(val * QSCALE);
                } else if (m == 1) {
                    unsigned int pk = __builtin_amdgcn_cvt_pk_fp8_f32(val, val, 0, false);
                    kv8[(size_t)r * 256 + col] = (unsigned char)(pk & 0xff);
                } else if (m == 2) {
                    unsigned int pk = __builtin_amdgcn_cvt_pk_fp8_f32(val, val, 0, false);
                    kv8[(size_t)r * 256 + 128 + col] = (unsigned char)(pk & 0xff);
                } else {
                    hsb[(size_t)r * 128 + col] = f2bf(val);
                }
            }
        }
    }
}

// ---------------------------------------------------------------- fc_before GEMM
__global__ __launch_bounds__(256) void k_gin(
    const float* __restrict__ x, int nrows,
    const unsigned short* __restrict__ Wt,   // [128col][64k]
    const float* __restrict__ bias,
    unsigned short* __restrict__ hb)
{
    const int tid = threadIdx.x;
    const int w = tid >> 6, lane = tid & 63;
    const int row0 = blockIdx.x * 64 + w * 16;
    const int lc = lane & 15, lk = lane >> 4;
    const int arow = row0 + lc;
    const bool rv = arow < nrows;

    bf16x8 a[2];
    #pragma unroll
    for (int kb = 0; kb < 2; ++kb) {
        union { bf16x8 v; unsigned short u[8]; } t;
        #pragma unroll
        for (int q = 0; q < 2; ++q) {
            float4 f = rv ? *(const float4*)(x + (size_t)arow * 64 + kb * 32 + lk * 8 + q * 4)
                          : make_float4(0.f, 0.f, 0.f, 0.f);
            t.u[q * 4 + 0] = f2bf(f.x); t.u[q * 4 + 1] = f2bf(f.y);
            t.u[q * 4 + 2] = f2bf(f.z); t.u[q * 4 + 3] = f2bf(f.w);
        }
        a[kb] = t.v;
    }

    const int cbase = lk * 4;
    #pragma unroll
    for (int ct = 0; ct < 8; ++ct) {
        const int bcol = ct * 16 + lc;
        f32x4 acc = {0.f, 0.f, 0.f, 0.f};
        #pragma unroll
        for (int kb = 0; kb < 2; ++kb) {
            bf16x8 b = *(const bf16x8*)(Wt + (size_t)bcol * 64 + kb * 32 + lk * 8);
            acc = __builtin_amdgcn_mfma_f32_16x16x32_bf16(a[kb], b, acc, 0, 0, 0);
        }
        const float bv_ = bias[bcol];
        #pragma unroll
        for (int i = 0; i < 4; ++i) {
            int r = row0 + cbase + i;
            if (r >= nrows) continue;
            hb[(size_t)r * 128 + bcol] = f2bf(fmaxf(acc[i] + bv_, 0.f));
        }
    }
}

// ---------------------------------------------------------------- fused attention
// One wave per dst node. Lane = (head h = lane>>3) x (edge slot j = lane&7).
// kv gathered as fp8-e4m3 (16B k + 16B v per head per edge). Fixed-shift
// softmax in exp2 domain (q pre-scaled by 0.25*log2e). Edge embedding
// factored: p = q.k + dist*qwe ; out_v = sum(w*v) + we*sum(w*dist).
#define LOADB(bi, kw, vw, dd, vv) {                                       \
    int rel_ = (bi) * 8 + j;                                              \
    vv = rel_ < cnt;                                                      \
    if (vv) {                                                             \
        int2 e2_ = srcd[beg + rel_];                                      \
        dd = __int_as_float(e2_.y);                                       \
        const unsigned char* kr_ = kvb + (size_t)e2_.x * 256 + h * 16;    \
        *(uint4*)(kw) = *(const uint4*)(kr_);                             \
        *(uint4*)(vw) = *(const uint4*)(kr_ + 128);                       \
    } else {                                                              \
        dd = 0.f;                                                         \
        _Pragma("unroll")                                                 \
        for (int z_ = 0; z_ < 4; ++z_) { (kw)[z_] = 0u; (vw)[z_] = 0u; }  \
    } }

#define COMPB(kw, vw, dd, vv) {                                           \
    float p_ = 0.f;                                                       \
    _Pragma("unroll")                                                     \
    for (int w4 = 0; w4 < 4; ++w4) {                                      \
        f32x2 k01_ = __builtin_amdgcn_cvt_pk_f32_fp8((kw)[w4], false);    \
        f32x2 k23_ = __builtin_amdgcn_cvt_pk_f32_fp8((kw)[w4], true);     \
        p_ = fmaf(qf[4 * w4 + 0], k01_.x, p_);                            \
        p_ = fmaf(qf[4 * w4 + 1], k01_.y, p_);                            \
        p_ = fmaf(qf[4 * w4 + 2], k23_.x, p_);                            \
        p_ = fmaf(qf[4 * w4 + 3], k23_.y, p_);                            \
    }                                                                     \
    p_ = fmaf(dd, qwe, p_);                                               \
    float wgt_ = (vv) ? exp2f(p_) : 0.f;                                  \
    s += wgt_;                                                            \
    sd = fmaf(dd, wgt_, sd);                                              \
    _Pragma("unroll")                                                     \
    for (int w4 = 0; w4 < 4; ++w4) {                                      \
        f32x2 v01_ = __builtin_amdgcn_cvt_pk_f32_fp8((vw)[w4], false);    \
        f32x2 v23_ = __builtin_amdgcn_cvt_pk_f32_fp8((vw)[w4], true);     \
        vacc[4 * w4 + 0] = fmaf(v01_.x, wgt_, vacc[4 * w4 + 0]);          \
        vacc[4 * w4 + 1] = fmaf(v01_.y, wgt_, vacc[4 * w4 + 1]);          \
        vacc[4 * w4 + 2] = fmaf(v23_.x, wgt_, vacc[4 * w4 + 2]);          \
        vacc[4 * w4 + 3] = fmaf(v23_.y, wgt_, vacc[4 * w4 + 3]);          \
    } }

template <int LAST>
__global__ __launch_bounds__(256) void k_attn(
    const unsigned short* __restrict__ qb,
    const unsigned short* __restrict__ hsb,
    const unsigned char* __restrict__ kvb,
    const int2* __restrict__ srcd,
    const float* __restrict__ We,
    const int* __restrict__ row_ptr,
    const float* __restrict__ lng,
    const float* __restrict__ lnb,
    unsigned short* __restrict__ hb,
    const float* __restrict__ Wat,     // [10][128] (LAST)
    const float* __restrict__ ba,      // [10]      (LAST)
    float* __restrict__ out, int nnodes)
{
    const int wid = threadIdx.x >> 6;
    const int lane = threadIdx.x & 63;
    const int n = blockIdx.x * 4 + wid;
    if (n >= nnodes) return;
    const int h = lane >> 3, j = lane & 7;
    const int c0 = lane * 2;

    // per-head scaled q (16 dims) in registers
    unsigned int uq[8];
    *(uint4*)(uq)     = *(const uint4*)(qb + (size_t)n * 128 + h * 16);
    *(uint4*)(uq + 4) = *(const uint4*)(qb + (size_t)n * 128 + h * 16 + 8);
    float qf[16];
    #pragma unroll
    for (int d = 0; d < 8; ++d) {
        qf[2 * d]     = lo16f(uq[d]);
        qf[2 * d + 1] = hi16f(uq[d]);
    }
    // qwe = q_scaled . we_head  (compile-time indices only)
    float qwe = 0.f;
    #pragma unroll
    for (int d4 = 0; d4 < 4; ++d4) {
        float4 wv = *(const float4*)(We + h * 16 + d4 * 4);
        qwe = fmaf(qf[d4 * 4 + 0], wv.x, qwe);
        qwe = fmaf(qf[d4 * 4 + 1], wv.y, qwe);
        qwe = fmaf(qf[d4 * 4 + 2], wv.z, qwe);
        qwe = fmaf(qf[d4 * 4 + 3], wv.w, qwe);
    }

    const int beg = row_ptr[n];
    const int cnt = row_ptr[n + 1] - beg;
    float s = 0.f, sd = 0.f;
    float vacc[16];
    #pragma unroll
    for (int d = 0; d < 16; ++d) vacc[d] = 0.f;

    if (cnt > 0) {
        const int nbatch = (cnt + 7) >> 3;
        unsigned int kwA[4], vwA[4], kwB[4], vwB[4], kwC[4], vwC[4];
        float dA = 0.f, dB = 0.f, dC = 0.f;
        bool vA = false, vB = false, vC = false;
        LOADB(0, kwA, vwA, dA, vA);
        if (1 < nbatch) LOADB(1, kwB, vwB, dB, vB);
        int b = 0;
        while (true) {
            if (b + 2 < nbatch) LOADB(b + 2, kwC, vwC, dC, vC);
            COMPB(kwA, vwA, dA, vA);
            if (++b >= nbatch) break;
            if (b + 2 < nbatch) LOADB(b + 2, kwA, vwA, dA, vA);
            COMPB(kwB, vwB, dB, vB);
            if (++b >= nbatch) break;
            if (b + 2 < nbatch) LOADB(b + 2, kwB, vwB, dB, vB);
            COMPB(kwC, vwC, dC, vC);
            if (++b >= nbatch) break;
        }
    }

    // reduce s, sd across the 8 slots of this head
    #pragma unroll
    for (int msk = 1; msk < 8; msk <<= 1) {
        s  += __shfl_xor(s, msk);
        sd += __shfl_xor(sd, msk);
    }
    // transpose-reduce vacc: lane (h,j) ends with dims {2j, 2j+1} of head h
    const bool b4 = (lane & 4) != 0;
    float c8[8];
    #pragma unroll
    for (int i = 0; i < 8; ++i) {
        float sendv = b4 ? vacc[i] : vacc[8 + i];
        float keep  = b4 ? vacc[8 + i] : vacc[i];
        c8[i] = keep + __shfl_xor(sendv, 4);
    }
    const bool b2 = (lane & 2) != 0;
    float c4[4];
    #pragma unroll
    for (int i = 0; i < 4; ++i) {
        float sendv = b2 ? c8[i] : c8[4 + i];
        float keep  = b2 ? c8[4 + i] : c8[i];
        c4[i] = keep + __shfl_xor(sendv, 2);
    }
    const bool b1 = (lane & 1) != 0;
    float c2[2];
    #pragma unroll
    for (int i = 0; i < 2; ++i) {
        float sendv = b1 ? c4[i] : c4[2 + i];
        float keep  = b1 ? c4[2 + i] : c4[i];
        c2[i] = keep + __shfl_xor(sendv, 1);
    }

    const float inv = 1.f / (s + 1e-16f);
    const float we0 = We[c0], we1 = We[c0 + 1];
    const ushort2 hu = *(const ushort2*)(hsb + (size_t)n * 128 + c0);
    float o0 = fmaf(fmaf(we0, sd, c2[0]), inv, bf2f(hu.x));
    float o1 = fmaf(fmaf(we1, sd, c2[1]), inv, bf2f(hu.y));

    // LayerNorm over 128 features + ReLU
    float t = o0 + o1;
    #pragma unroll
    for (int off = 1; off < 64; off <<= 1) t += __shfl_xor(t, off);
    float mean = t * 0.0078125f;
    float d0 = o0 - mean, d1 = o1 - mean;
    float vv2 = d0 * d0 + d1 * d1;
    #pragma unroll
    for (int off = 1; off < 64; off <<= 1) vv2 += __shfl_xor(vv2, off);
    float rstd = rsqrtf(vv2 * 0.0078125f + 1e-5f);
    float y0 = fmaxf(d0 * rstd * lng[c0] + lnb[c0], 0.f);
    float y1 = fmaxf(d1 * rstd * lng[c0 + 1] + lnb[c0 + 1], 0.f);

    if (LAST) {
        // fused fc_after + log_softmax
        float lg[NCLS];
        #pragma unroll
        for (int c = 0; c < NCLS; ++c) {
            float2 wv = *(const float2*)(Wat + c * 128 + c0);
            float p = fmaf(y0, wv.x, y1 * wv.y);
            #pragma unroll
            for (int msk = 1; msk < 64; msk <<= 1) p += __shfl_xor(p, msk);
            lg[c] = p + ba[c];
        }
        float mx = lg[0];
        #pragma unroll
        for (int c = 1; c < NCLS; ++c) mx = fmaxf(mx, lg[c]);
        float sum = 0.f;
        #pragma unroll
        for (int c = 0; c < NCLS; ++c) sum += __expf(lg[c] - mx);
        float lse = mx + __logf(sum);
        if (lane == 0) {
            #pragma unroll
            for (int c = 0; c < NCLS; ++c) out[(size_t)n * NCLS + c] = lg[c] - lse;
        }
    } else {
        ushort2 o;
        o.x = f2bf(y0);
        o.y = f2bf(y1);
        *(ushort2*)(hb + (size_t)n * 128 + c0) = o;
    }
}

// ---------------------------------------------------------------- launch
extern "C" void kernel_launch(void* const* d_in, const int* in_sizes, int n_in,
                              void* d_out, int out_size, void* d_ws, size_t ws_size,
                              hipStream_t stream)
{
    const float* x    = (const float*)d_in[0];
    const int*   ei   = (const int*)d_in[1];
    const float* dist = (const float*)d_in[2];
    const float* Wq   = (const float*)d_in[3];
    const float* bq   = (const float*)d_in[4];
    const float* Wk   = (const float*)d_in[5];
    const float* bk   = (const float*)d_in[6];
    const float* Wv   = (const float*)d_in[7];
    const float* bv   = (const float*)d_in[8];
    const float* We   = (const float*)d_in[9];
    const float* Wsk  = (const float*)d_in[10];
    const float* bs   = (const float*)d_in[11];
    const float* lng  = (const float*)d_in[12];
    const float* lnb  = (const float*)d_in[13];
    const float* Wbe  = (const float*)d_in[14];
    const float* bbe  = (const float*)d_in[15];
    const float* Waf  = (const float*)d_in[16];
    const float* baf  = (const float*)d_in[17];
    float* out = (float*)d_out;
    const int* esrc = ei;
    const int* edst = ei + NE;

    char* ws = (char*)d_ws;
    size_t off = 0;
    unsigned short* qb  = (unsigned short*)(ws + off); off += 12800000;
    unsigned short* hsb = (unsigned short*)(ws + off); off += 12800000;
    unsigned char*  kv8 = (unsigned char*)(ws + off);  off += 12800000;
    unsigned short* hb  = (unsigned short*)(ws + off); off += 12800000;
    unsigned short* Wt12 = (unsigned short*)(ws + off); off += 393216;
    unsigned short* Wbt  = (unsigned short*)(ws + off); off += 16384;
    float* Wat = (float*)(ws + off);   off += 5120;
    int* counts   = (int*)(ws + off);  off += 200192;
    int* cursor   = (int*)(ws + off);  off += 200192;
    int* row_ptr  = (int*)(ws + off);  off += 200192;
    int* partials = (int*)(ws + off);  off += 512;
    int2* srcd    = (int2*)(ws + off); off += (size_t)NE * 8;

    // CSR build (row_ptr has NN+1 entries)
    hipMemsetAsync(counts, 0, (NN + 1) * sizeof(int), stream);
    hipMemsetAsync(cursor, 0, NN * sizeof(int), stream);
    k_count<<<(NE + 255) / 256, 256, 0, stream>>>(edst, counts);
    int nsb = (NN + 1 + 511) / 512;   // 98
    k_scan1<<<nsb, 512, 0, stream>>>(counts, row_ptr, partials, NN + 1);
    k_scan2<<<1, 128, 0, stream>>>(partials, nsb);
    k_scan3<<<nsb, 512, 0, stream>>>(row_ptr, partials, NN + 1);
    k_fill<<<(NE + 255) / 256, 256, 0, stream>>>(esrc, edst, dist, cursor, row_ptr, srcd);

    // weight prep (merged)
    k_wprep<<<805, 256, 0, stream>>>(Wq, Wk, Wv, Wsk, Wbe, Waf, Wt12, Wbt, Wat);

    const int ngb = (NN + 63) / 64;   // 782

    // h = relu(x @ W_before + b_before)  -> hb (bf16); converts f32 x inline
    k_gin<<<ngb, 256, 0, stream>>>(x, NN, Wbt, bbe, hb);

    for (int l = 0; l < NLAYER; ++l) {
        const unsigned short* wt = Wt12 + (size_t)l * 4 * 16384;
        k_qkvs<<<ngb, 512, 0, stream>>>(hb, NN, wt,
            bq + l * HID, bk + l * HID, bv + l * HID, bs + l * HID,
            qb, kv8, hsb);
        if (l < NLAYER - 1) {
            k_attn<0><<<(NN + 3) / 4, 256, 0, stream>>>(qb, hsb, kv8, srcd, We + l * HID,
                row_ptr, lng + l * HID, lnb + l * HID, hb, nullptr, nullptr, nullptr, NN);
        } else {
            k_attn<1><<<(NN + 3) / 4, 256, 0, stream>>>(qb, hsb, kv8, srcd, We + l * HID,
                row_ptr, lng + l * HID, lnb + l * HID, hb, Wat, baf, out, NN);
        }
    }
}

// Round 6
// 345.773 us; speedup vs baseline: 2.3482x; 1.1455x over previous
//
#include <hip/hip_runtime.h>
#include <cstdint>
#include <cstddef>

#define NN 50000
#define NE 600000
#define FIN 64
#define HID 128
#define NCLS 10
#define NLAYER 3

// 0.25 (1/sqrt(16)) * log2(e)  -> softmax exp becomes a single exp2
#define QSCALE 0.36067376022224085f

typedef __bf16 bf16x8 __attribute__((ext_vector_type(8)));
typedef float f32x4 __attribute__((ext_vector_type(4)));
typedef float f32x2 __attribute__((ext_vector_type(2)));

__device__ __forceinline__ unsigned short f2bf(float f) {
    unsigned int u = __builtin_bit_cast(unsigned int, f);
    u += 0x7fffu + ((u >> 16) & 1u);
    return (unsigned short)(u >> 16);
}
__device__ __forceinline__ float bf2f(unsigned short s) {
    unsigned int u = ((unsigned int)s) << 16;
    return __builtin_bit_cast(float, u);
}
__device__ __forceinline__ float lo16f(unsigned int w) {
    return __builtin_bit_cast(float, w << 16);
}
__device__ __forceinline__ float hi16f(unsigned int w) {
    return __builtin_bit_cast(float, w & 0xffff0000u);
}

// ---------------------------------------------------------------- prep: weights + count
// blocks 0..767: 12x [128][128] f32 -> bf16 [l][{q,k,v,s}][col][k]
// blocks 768..799: W_before [64][128] -> bf16 [128col][64k]
// blocks 800..804: W_after [128][10] -> f32 [10][128]
// blocks 805.. : histogram of edge dst
__global__ __launch_bounds__(256) void k_prep(
    const float* __restrict__ Wq, const float* __restrict__ Wk,
    const float* __restrict__ Wv, const float* __restrict__ Ws,
    const float* __restrict__ Wbe, const float* __restrict__ Waf,
    unsigned short* __restrict__ Wt12,
    unsigned short* __restrict__ Wbt,
    float* __restrict__ Wat,
    const int* __restrict__ edst, int* __restrict__ counts)
{
    int blk = blockIdx.x;
    int tid = threadIdx.x;
    if (blk < 768) {
        int m = blk >> 6;                 // 0..11
        int l = m >> 2, which = m & 3;
        const float* src;
        if (which == 0) src = Wq; else if (which == 1) src = Wk;
        else if (which == 2) src = Wv; else src = Ws;
        src += (size_t)l * HID * HID;
        int idx = (blk & 63) * 256 + tid; // 0..16383
        int c = idx >> 7, k = idx & 127;
        Wt12[(size_t)m * 16384 + (size_t)c * 128 + k] = f2bf(src[(size_t)k * 128 + c]);
    } else if (blk < 800) {
        int idx = (blk - 768) * 256 + tid;  // 0..8191
        int c = idx >> 6, k = idx & 63;
        Wbt[(size_t)c * 64 + k] = f2bf(Wbe[(size_t)k * 128 + c]);
    } else if (blk < 805) {
        int i = (blk - 800) * 256 + tid;    // 0..1279
        if (i < 1280) {
            int c = i >> 7, f = i & 127;
            Wat[i] = Waf[f * 10 + c];
        }
    } else {
        int e = (blk - 805) * 256 + tid;
        if (e < NE) atomicAdd(&counts[edst[e]], 1);
    }
}

// ---------------------------------------------------------------- CSR scan/fill
__global__ __launch_bounds__(512) void k_scan1(const int* __restrict__ counts,
                                               int* __restrict__ row_ptr,
                                               int* __restrict__ partials, int n) {
    __shared__ int sm[512];
    int tid = threadIdx.x;
    int i = blockIdx.x * 512 + tid;
    int v = (i < n) ? counts[i] : 0;
    sm[tid] = v;
    __syncthreads();
    #pragma unroll
    for (int off = 1; off < 512; off <<= 1) {
        int t = (tid >= off) ? sm[tid - off] : 0;
        __syncthreads();
        sm[tid] += t;
        __syncthreads();
    }
    if (i < n) row_ptr[i] = sm[tid] - v;
    if (tid == 511) partials[blockIdx.x] = sm[511];
}

__global__ __launch_bounds__(128) void k_scan2(int* __restrict__ partials, int nb) {
    __shared__ int sm[128];
    int t = threadIdx.x;
    int v = (t < nb) ? partials[t] : 0;
    sm[t] = v;
    __syncthreads();
    #pragma unroll
    for (int off = 1; off < 128; off <<= 1) {
        int x = (t >= off) ? sm[t - off] : 0;
        __syncthreads();
        sm[t] += x;
        __syncthreads();
    }
    if (t < nb) partials[t] = sm[t] - v;   // exclusive
}

__global__ __launch_bounds__(512) void k_scan3(int* __restrict__ row_ptr,
                                               const int* __restrict__ partials, int n) {
    int i = blockIdx.x * 512 + threadIdx.x;
    if (i < n) row_ptr[i] += partials[blockIdx.x];
}

__global__ __launch_bounds__(256) void k_fill(const int* __restrict__ esrc,
                                              const int* __restrict__ edst,
                                              const float* __restrict__ dist,
                                              int* __restrict__ cursor,
                                              const int* __restrict__ row_ptr,
                                              int2* __restrict__ srcd) {
    int e = blockIdx.x * 256 + threadIdx.x;
    if (e < NE) {
        int d = edst[e];
        int pos = atomicAdd(&cursor[d], 1);
        srcd[row_ptr[d] + pos] = make_int2(esrc[e], __float_as_int(dist[e]));
    }
}

// ---------------------------------------------------------------- fused QKVS GEMM
// 8 waves; wave w: matrix m=w>>1 (q,k,v,s), column-half ch=w&1.
// MFMA operands SWAPPED (W fragment as M-side) so each lane's acc holds 4
// consecutive COLS of one row -> vector stores (ushort4 / fp8-dword).
__global__ __launch_bounds__(512) void k_qkvs(
    const unsigned short* __restrict__ Ab, int nrows,
    const unsigned short* __restrict__ Wt,   // [4][128col][128k]
    const float* __restrict__ bq, const float* __restrict__ bk,
    const float* __restrict__ bv, const float* __restrict__ bs,
    unsigned short* __restrict__ qb,
    unsigned char* __restrict__ kv8,         // [node][k 128B | v 128B]
    unsigned short* __restrict__ hsb)
{
    const int tid = threadIdx.x;
    const int w = tid >> 6, lane = tid & 63;
    const int m = w >> 1, ch = w & 1;
    const float* bias = (m == 0) ? bq : (m == 1) ? bk : (m == 2) ? bv : bs;
    const unsigned short* Wm = Wt + (size_t)m * 16384;
    const int lc = lane & 15, lk = lane >> 4;

    bf16x8 bw[4][4];
    float4 bb[4];
    #pragma unroll
    for (int ct = 0; ct < 4; ++ct) {
        int col = ch * 64 + ct * 16 + lc;
        bb[ct] = *(const float4*)(bias + ch * 64 + ct * 16 + lk * 4);
        #pragma unroll
        for (int kb = 0; kb < 4; ++kb)
            bw[ct][kb] = *(const bf16x8*)(Wm + (size_t)col * 128 + kb * 32 + lk * 8);
    }

    const int r0 = blockIdx.x * 64;
    #pragma unroll
    for (int rt = 0; rt < 4; ++rt) {
        const int arow = r0 + rt * 16 + lc;
        const bool rv = arow < nrows;
        bf16x8 z = {};
        bf16x8 a[4];
        #pragma unroll
        for (int kb = 0; kb < 4; ++kb)
            a[kb] = rv ? *(const bf16x8*)(Ab + (size_t)arow * 128 + kb * 32 + lk * 8) : z;
        #pragma unroll
        for (int ct = 0; ct < 4; ++ct) {
            f32x4 acc = {0.f, 0.f, 0.f, 0.f};
            #pragma unroll
            for (int kb = 0; kb < 4; ++kb)
                acc = __builtin_amdgcn_mfma_f32_16x16x32_bf16(bw[ct][kb], a[kb], acc, 0, 0, 0);
            if (rv) {
                const int colb = ch * 64 + ct * 16 + lk * 4;
                float v0 = acc[0] + bb[ct].x, v1 = acc[1] + bb[ct].y;
                float v2 = acc[2] + bb[ct].z, v3 = acc[3] + bb[ct].w;
                if (m == 0) {
                    ushort4 o;
                    o.x = f2bf(v0 * QSCALE); o.y = f2bf(v1 * QSCALE);
                    o.z = f2bf(v2 * QSCALE); o.w = f2bf(v3 * QSCALE);
                    *(ushort4*)(qb + (size_t)arow * 128 + colb) = o;
                } else if (m == 1 || m == 2) {
                    unsigned int pk = __builtin_amdgcn_cvt_pk_fp8_f32(v0, v1, 0, false);
                    pk = __builtin_amdgcn_cvt_pk_fp8_f32(v2, v3, pk, true);
                    *(unsigned int*)(kv8 + (size_t)arow * 256 + (m == 2 ? 128 : 0) + colb) = pk;
                } else {
                    ushort4 o;
                    o.x = f2bf(v0); o.y = f2bf(v1); o.z = f2bf(v2); o.w = f2bf(v3);
                    *(ushort4*)(hsb + (size_t)arow * 128 + colb) = o;
                }
            }
        }
    }
}

// ---------------------------------------------------------------- fc_before GEMM (transposed store)
__global__ __launch_bounds__(256) void k_gin(
    const float* __restrict__ x, int nrows,
    const unsigned short* __restrict__ Wt,   // [128col][64k]
    const float* __restrict__ bias,
    unsigned short* __restrict__ hb)
{
    const int tid = threadIdx.x;
    const int w = tid >> 6, lane = tid & 63;
    const int lc = lane & 15, lk = lane >> 4;
    const int arow = blockIdx.x * 64 + w * 16 + lc;
    const bool rv = arow < nrows;

    bf16x8 a[2];
    #pragma unroll
    for (int kb = 0; kb < 2; ++kb) {
        union { bf16x8 v; unsigned short u[8]; } t;
        #pragma unroll
        for (int q = 0; q < 2; ++q) {
            float4 f = rv ? *(const float4*)(x + (size_t)arow * 64 + kb * 32 + lk * 8 + q * 4)
                          : make_float4(0.f, 0.f, 0.f, 0.f);
            t.u[q * 4 + 0] = f2bf(f.x); t.u[q * 4 + 1] = f2bf(f.y);
            t.u[q * 4 + 2] = f2bf(f.z); t.u[q * 4 + 3] = f2bf(f.w);
        }
        a[kb] = t.v;
    }

    #pragma unroll
    for (int ct = 0; ct < 8; ++ct) {
        f32x4 acc = {0.f, 0.f, 0.f, 0.f};
        #pragma unroll
        for (int kb = 0; kb < 2; ++kb) {
            bf16x8 bwf = *(const bf16x8*)(Wt + (size_t)(ct * 16 + lc) * 64 + kb * 32 + lk * 8);
            acc = __builtin_amdgcn_mfma_f32_16x16x32_bf16(bwf, a[kb], acc, 0, 0, 0);
        }
        if (rv) {
            float4 bv_ = *(const float4*)(bias + ct * 16 + lk * 4);
            ushort4 o;
            o.x = f2bf(fmaxf(acc[0] + bv_.x, 0.f));
            o.y = f2bf(fmaxf(acc[1] + bv_.y, 0.f));
            o.z = f2bf(fmaxf(acc[2] + bv_.z, 0.f));
            o.w = f2bf(fmaxf(acc[3] + bv_.w, 0.f));
            *(ushort4*)(hb + (size_t)arow * 128 + ct * 16 + lk * 4) = o;
        }
    }
}

// ---------------------------------------------------------------- fused attention
// One wave per PAIR of dst nodes. Lane = (head h = lane>>3) x (slot j = lane&7).
// Pair's edge list loaded densely into a 128-edge register window (shfl
// broadcast); kv gathered fp8-e4m3; fixed-shift softmax in exp2 domain.
#define EFETCH(relbase, t, cntN, kw, vw, dd, vv) {                        \
    int rel_ = (relbase) + (t) * 8 + j;                                   \
    vv = (t) * 8 + j < (cntN);                                            \
    int r6_ = rel_ & 63;                                                  \
    int ax_ = __shfl(w0.x, r6_), ay_ = __shfl(w0.y, r6_);                 \
    int bx_ = __shfl(w1.x, r6_), by_ = __shfl(w1.y, r6_);                 \
    int sx_ = rel_ < 64 ? ax_ : bx_;                                      \
    int sy_ = rel_ < 64 ? ay_ : by_;                                      \
    if (vv && rel_ >= 128) {                                              \
        int2 e2_ = srcd[beg0 + rel_];                                     \
        sx_ = e2_.x; sy_ = e2_.y;                                         \
    }                                                                     \
    dd = vv ? __int_as_float(sy_) : 0.f;                                  \
    if (vv) {                                                             \
        const unsigned char* kr_ = kvb + (size_t)sx_ * 256 + h * 16;      \
        *(uint4*)(kw) = *(const uint4*)(kr_);                             \
        *(uint4*)(vw) = *(const uint4*)(kr_ + 128);                       \
    } else {                                                              \
        _Pragma("unroll")                                                 \
        for (int z_ = 0; z_ < 4; ++z_) { (kw)[z_] = 0u; (vw)[z_] = 0u; }  \
    } }

#define COMPB(kw, vw, dd, vv, qf, qwe, s, sd, vacc) {                     \
    float p_ = 0.f;                                                       \
    _Pragma("unroll")                                                     \
    for (int w4 = 0; w4 < 4; ++w4) {                                      \
        f32x2 k01_ = __builtin_amdgcn_cvt_pk_f32_fp8((kw)[w4], false);    \
        f32x2 k23_ = __builtin_amdgcn_cvt_pk_f32_fp8((kw)[w4], true);     \
        p_ = fmaf(qf[4 * w4 + 0], k01_.x, p_);                            \
        p_ = fmaf(qf[4 * w4 + 1], k01_.y, p_);                            \
        p_ = fmaf(qf[4 * w4 + 2], k23_.x, p_);                            \
        p_ = fmaf(qf[4 * w4 + 3], k23_.y, p_);                            \
    }                                                                     \
    p_ = fmaf(dd, qwe, p_);                                               \
    float wgt_ = (vv) ? exp2f(p_) : 0.f;                                  \
    s += wgt_;                                                            \
    sd = fmaf(dd, wgt_, sd);                                              \
    _Pragma("unroll")                                                     \
    for (int w4 = 0; w4 < 4; ++w4) {                                      \
        f32x2 v01_ = __builtin_amdgcn_cvt_pk_f32_fp8((vw)[w4], false);    \
        f32x2 v23_ = __builtin_amdgcn_cvt_pk_f32_fp8((vw)[w4], true);     \
        vacc[4 * w4 + 0] = fmaf(v01_.x, wgt_, vacc[4 * w4 + 0]);          \
        vacc[4 * w4 + 1] = fmaf(v01_.y, wgt_, vacc[4 * w4 + 1]);          \
        vacc[4 * w4 + 2] = fmaf(v23_.x, wgt_, vacc[4 * w4 + 2]);          \
        vacc[4 * w4 + 3] = fmaf(v23_.y, wgt_, vacc[4 * w4 + 3]);          \
    } }

template <int LAST>
__global__ __launch_bounds__(256, 4) void k_attn(
    const unsigned short* __restrict__ qb,
    const unsigned short* __restrict__ hsb,
    const unsigned char* __restrict__ kvb,
    const int2* __restrict__ srcd,
    const float* __restrict__ We,
    const int* __restrict__ row_ptr,
    const float* __restrict__ lng,
    const float* __restrict__ lnb,
    unsigned short* __restrict__ hb,
    const float* __restrict__ Wat,     // [10][128] (LAST)
    const float* __restrict__ ba,      // [10]      (LAST)
    float* __restrict__ out, int nnodes)
{
    const int wid = threadIdx.x >> 6;
    const int lane = threadIdx.x & 63;
    const int n0 = (blockIdx.x * 4 + wid) * 2;
    if (n0 >= nnodes) return;
    const int n1 = n0 + 1;
    const int h = lane >> 3, j = lane & 7;
    const int c0 = lane * 2;

    // row_ptr for the pair
    int rpv = 0;
    if (lane < 3) rpv = row_ptr[n0 + lane];
    const int beg0 = __shfl(rpv, 0);
    const int beg1 = __shfl(rpv, 1);
    const int end1 = __shfl(rpv, 2);
    const int cnt0 = beg1 - beg0;
    const int cnt1 = end1 - beg1;
    const int T = end1 - beg0;

    // dense 128-edge window
    int2 w0 = make_int2(0, 0), w1 = make_int2(0, 0);
    if (lane < T) w0 = srcd[beg0 + lane];
    if (64 + lane < T) w1 = srcd[beg0 + 64 + lane];

    // q for both nodes (pre-scaled bf16) + skip rows
    unsigned int uq0[8], uq1[8];
    *(uint4*)(uq0)     = *(const uint4*)(qb + (size_t)n0 * 128 + h * 16);
    *(uint4*)(uq0 + 4) = *(const uint4*)(qb + (size_t)n0 * 128 + h * 16 + 8);
    *(uint4*)(uq1)     = *(const uint4*)(qb + (size_t)n1 * 128 + h * 16);
    *(uint4*)(uq1 + 4) = *(const uint4*)(qb + (size_t)n1 * 128 + h * 16 + 8);
    const ushort2 hu0 = *(const ushort2*)(hsb + (size_t)n0 * 128 + c0);
    const ushort2 hu1 = *(const ushort2*)(hsb + (size_t)n1 * 128 + c0);

    float qf0[16], qf1[16];
    #pragma unroll
    for (int d = 0; d < 8; ++d) {
        qf0[2 * d] = lo16f(uq0[d]); qf0[2 * d + 1] = hi16f(uq0[d]);
        qf1[2 * d] = lo16f(uq1[d]); qf1[2 * d + 1] = hi16f(uq1[d]);
    }
    float qwe0 = 0.f, qwe1 = 0.f;
    #pragma unroll
    for (int d4 = 0; d4 < 4; ++d4) {
        float4 wv = *(const float4*)(We + h * 16 + d4 * 4);
        qwe0 = fmaf(qf0[d4 * 4 + 0], wv.x, qwe0); qwe1 = fmaf(qf1[d4 * 4 + 0], wv.x, qwe1);
        qwe0 = fmaf(qf0[d4 * 4 + 1], wv.y, qwe0); qwe1 = fmaf(qf1[d4 * 4 + 1], wv.y, qwe1);
        qwe0 = fmaf(qf0[d4 * 4 + 2], wv.z, qwe0); qwe1 = fmaf(qf1[d4 * 4 + 2], wv.z, qwe1);
        qwe0 = fmaf(qf0[d4 * 4 + 3], wv.w, qwe0); qwe1 = fmaf(qf1[d4 * 4 + 3], wv.w, qwe1);
    }

    float s0 = 0.f, sd0 = 0.f, s1 = 0.f, sd1 = 0.f;
    float vacc0[16], vacc1[16];
    #pragma unroll
    for (int d = 0; d < 16; ++d) { vacc0[d] = 0.f; vacc1[d] = 0.f; }

    {
        const int nb0 = (cnt0 + 7) >> 3, nb1 = (cnt1 + 7) >> 3;
        unsigned int kA[4], vA[4], kB[4], vB[4], kC[4], vC[4], kD[4], vD[4];
        float dA, dB, dC, dD;
        bool eA, eB, eC, eD;
        // burst: first 2 batches of each node (8 gathers in flight)
        EFETCH(0,    0, cnt0, kA, vA, dA, eA);
        EFETCH(cnt0, 0, cnt1, kB, vB, dB, eB);
        EFETCH(0,    1, cnt0, kC, vC, dC, eC);
        EFETCH(cnt0, 1, cnt1, kD, vD, dD, eD);
        COMPB(kA, vA, dA, eA, qf0, qwe0, s0, sd0, vacc0);
        COMPB(kB, vB, dB, eB, qf1, qwe1, s1, sd1, vacc1);
        COMPB(kC, vC, dC, eC, qf0, qwe0, s0, sd0, vacc0);
        COMPB(kD, vD, dD, eD, qf1, qwe1, s1, sd1, vacc1);
        // rare tail (cnt > 16)
        const int tmax = nb0 > nb1 ? nb0 : nb1;
        for (int t = 2; t < tmax; ++t) {
            EFETCH(0,    t, cnt0, kA, vA, dA, eA);
            EFETCH(cnt0, t, cnt1, kB, vB, dB, eB);
            COMPB(kA, vA, dA, eA, qf0, qwe0, s0, sd0, vacc0);
            COMPB(kB, vB, dB, eB, qf1, qwe1, s1, sd1, vacc1);
        }
    }

    // reduce s, sd across the 8 slots of each head (both nodes interleaved)
    #pragma unroll
    for (int msk = 1; msk < 8; msk <<= 1) {
        s0  += __shfl_xor(s0, msk);  sd0 += __shfl_xor(sd0, msk);
        s1  += __shfl_xor(s1, msk);  sd1 += __shfl_xor(sd1, msk);
    }
    // transpose-reduce vacc: lane (h,j) ends with dims {2j,2j+1} of head h
    const bool b4 = (lane & 4) != 0;
    float c8a[8], c8b[8];
    #pragma unroll
    for (int i = 0; i < 8; ++i) {
        float sa = b4 ? vacc0[i] : vacc0[8 + i];
        float ka = b4 ? vacc0[8 + i] : vacc0[i];
        c8a[i] = ka + __shfl_xor(sa, 4);
        float sb = b4 ? vacc1[i] : vacc1[8 + i];
        float kb = b4 ? vacc1[8 + i] : vacc1[i];
        c8b[i] = kb + __shfl_xor(sb, 4);
    }
    const bool b2 = (lane & 2) != 0;
    float c4a[4], c4b[4];
    #pragma unroll
    for (int i = 0; i < 4; ++i) {
        float sa = b2 ? c8a[i] : c8a[4 + i];
        float ka = b2 ? c8a[4 + i] : c8a[i];
        c4a[i] = ka + __shfl_xor(sa, 2);
        float sb = b2 ? c8b[i] : c8b[4 + i];
        float kb = b2 ? c8b[4 + i] : c8b[i];
        c4b[i] = kb + __shfl_xor(sb, 2);
    }
    const bool b1 = (lane & 1) != 0;
    float c2a[2], c2b[2];
    #pragma unroll
    for (int i = 0; i < 2; ++i) {
        float sa = b1 ? c4a[i] : c4a[2 + i];
        float ka = b1 ? c4a[2 + i] : c4a[i];
        c2a[i] = ka + __shfl_xor(sa, 1);
        float sb = b1 ? c4b[i] : c4b[2 + i];
        float kb = b1 ? c4b[2 + i] : c4b[i];
        c2b[i] = kb + __shfl_xor(sb, 1);
    }

    const float inv0 = 1.f / (s0 + 1e-16f);
    const float inv1 = 1.f / (s1 + 1e-16f);
    const float2 wev = *(const float2*)(We + c0);
    float o00 = fmaf(fmaf(wev.x, sd0, c2a[0]), inv0, bf2f(hu0.x));
    float o01 = fmaf(fmaf(wev.y, sd0, c2a[1]), inv0, bf2f(hu0.y));
    float o10 = fmaf(fmaf(wev.x, sd1, c2b[0]), inv1, bf2f(hu1.x));
    float o11 = fmaf(fmaf(wev.y, sd1, c2b[1]), inv1, bf2f(hu1.y));

    // LayerNorm over 128 features + ReLU (both nodes interleaved)
    float t0 = o00 + o01, t1 = o10 + o11;
    #pragma unroll
    for (int off = 1; off < 64; off <<= 1) {
        t0 += __shfl_xor(t0, off);
        t1 += __shfl_xor(t1, off);
    }
    const float mean0 = t0 * 0.0078125f, mean1 = t1 * 0.0078125f;
    float d00 = o00 - mean0, d01 = o01 - mean0;
    float d10 = o10 - mean1, d11 = o11 - mean1;
    float v0 = d00 * d00 + d01 * d01, v1 = d10 * d10 + d11 * d11;
    #pragma unroll
    for (int off = 1; off < 64; off <<= 1) {
        v0 += __shfl_xor(v0, off);
        v1 += __shfl_xor(v1, off);
    }
    const float rstd0 = rsqrtf(v0 * 0.0078125f + 1e-5f);
    const float rstd1 = rsqrtf(v1 * 0.0078125f + 1e-5f);
    const float2 g2 = *(const float2*)(lng + c0);
    const float2 be2 = *(const float2*)(lnb + c0);
    float y00 = fmaxf(fmaf(d00 * rstd0, g2.x, be2.x), 0.f);
    float y01 = fmaxf(fmaf(d01 * rstd0, g2.y, be2.y), 0.f);
    float y10 = fmaxf(fmaf(d10 * rstd1, g2.x, be2.x), 0.f);
    float y11 = fmaxf(fmaf(d11 * rstd1, g2.y, be2.y), 0.f);

    if (LAST) {
        float lg0[NCLS], lg1[NCLS];
        #pragma unroll
        for (int c = 0; c < NCLS; ++c) {
            float2 wv = *(const float2*)(Wat + c * 128 + c0);
            float p0 = fmaf(y00, wv.x, y01 * wv.y);
            float p1 = fmaf(y10, wv.x, y11 * wv.y);
            #pragma unroll
            for (int msk = 1; msk < 64; msk <<= 1) {
                p0 += __shfl_xor(p0, msk);
                p1 += __shfl_xor(p1, msk);
            }
            lg0[c] = p0 + ba[c];
            lg1[c] = p1 + ba[c];
        }
        float mx0 = lg0[0], mx1 = lg1[0];
        #pragma unroll
        for (int c = 1; c < NCLS; ++c) { mx0 = fmaxf(mx0, lg0[c]); mx1 = fmaxf(mx1, lg1[c]); }
        float su0 = 0.f, su1 = 0.f;
        #pragma unroll
        for (int c = 0; c < NCLS; ++c) { su0 += __expf(lg0[c] - mx0); su1 += __expf(lg1[c] - mx1); }
        float lse0 = mx0 + __logf(su0), lse1 = mx1 + __logf(su1);
        if (lane == 0) {
            #pragma unroll
            for (int c = 0; c < NCLS; ++c) {
                out[(size_t)n0 * NCLS + c] = lg0[c] - lse0;
                out[(size_t)n1 * NCLS + c] = lg1[c] - lse1;
            }
        }
    } else {
        ushort2 oa, ob;
        oa.x = f2bf(y00); oa.y = f2bf(y01);
        ob.x = f2bf(y10); ob.y = f2bf(y11);
        *(ushort2*)(hb + (size_t)n0 * 128 + c0) = oa;
        *(ushort2*)(hb + (size_t)n1 * 128 + c0) = ob;
    }
}

// ---------------------------------------------------------------- launch
extern "C" void kernel_launch(void* const* d_in, const int* in_sizes, int n_in,
                              void* d_out, int out_size, void* d_ws, size_t ws_size,
                              hipStream_t stream)
{
    const float* x    = (const float*)d_in[0];
    const int*   ei   = (const int*)d_in[1];
    const float* dist = (const float*)d_in[2];
    const float* Wq   = (const float*)d_in[3];
    const float* bq   = (const float*)d_in[4];
    const float* Wk   = (const float*)d_in[5];
    const float* bk   = (const float*)d_in[6];
    const float* Wv   = (const float*)d_in[7];
    const float* bv   = (const float*)d_in[8];
    const float* We   = (const float*)d_in[9];
    const float* Wsk  = (const float*)d_in[10];
    const float* bs   = (const float*)d_in[11];
    const float* lng  = (const float*)d_in[12];
    const float* lnb  = (const float*)d_in[13];
    const float* Wbe  = (const float*)d_in[14];
    const float* bbe  = (const float*)d_in[15];
    const float* Waf  = (const float*)d_in[16];
    const float* baf  = (const float*)d_in[17];
    float* out = (float*)d_out;
    const int* esrc = ei;
    const int* edst = ei + NE;

    char* ws = (char*)d_ws;
    size_t off = 0;
    unsigned short* qb  = (unsigned short*)(ws + off); off += 12800000;
    unsigned short* hsb = (unsigned short*)(ws + off); off += 12800000;
    unsigned char*  kv8 = (unsigned char*)(ws + off);  off += 12800000;
    unsigned short* hb  = (unsigned short*)(ws + off); off += 12800000;
    unsigned short* Wt12 = (unsigned short*)(ws + off); off += 393216;
    unsigned short* Wbt  = (unsigned short*)(ws + off); off += 16384;
    float* Wat = (float*)(ws + off);   off += 5120;
    int* counts   = (int*)(ws + off);  off += 200192;   // NN+1 used
    int* cursor   = (int*)(ws + off);  off += 200192;   // adjacent to counts
    int* row_ptr  = (int*)(ws + off);  off += 200192;
    int* partials = (int*)(ws + off);  off += 512;
    int2* srcd    = (int2*)(ws + off); off += (size_t)NE * 8;

    // zero counts (+pad) and cursor in ONE memset (adjacent regions)
    hipMemsetAsync(counts, 0, 2 * 200192, stream);
    // weight prep + dst histogram
    k_prep<<<805 + (NE + 255) / 256, 256, 0, stream>>>(
        Wq, Wk, Wv, Wsk, Wbe, Waf, Wt12, Wbt, Wat, edst, counts);
    int nsb = (NN + 1 + 511) / 512;   // 98
    k_scan1<<<nsb, 512, 0, stream>>>(counts, row_ptr, partials, NN + 1);
    k_scan2<<<1, 128, 0, stream>>>(partials, nsb);
    k_scan3<<<nsb, 512, 0, stream>>>(row_ptr, partials, NN + 1);
    k_fill<<<(NE + 255) / 256, 256, 0, stream>>>(esrc, edst, dist, cursor, row_ptr, srcd);

    const int ngb = (NN + 63) / 64;   // 782

    // h = relu(x @ W_before + b_before)  -> hb (bf16); converts f32 x inline
    k_gin<<<ngb, 256, 0, stream>>>(x, NN, Wbt, bbe, hb);

    for (int l = 0; l < NLAYER; ++l) {
        const unsigned short* wt = Wt12 + (size_t)l * 4 * 16384;
        k_qkvs<<<ngb, 512, 0, stream>>>(hb, NN, wt,
            bq + l * HID, bk + l * HID, bv + l * HID, bs + l * HID,
            qb, kv8, hsb);
        const int nab = (NN / 2 + 3) / 4;   // 6250
        if (l < NLAYER - 1) {
            k_attn<0><<<nab, 256, 0, stream>>>(qb, hsb, kv8, srcd, We + l * HID,
                row_ptr, lng + l * HID, lnb + l * HID, hb, nullptr, nullptr, nullptr, NN);
        } else {
            k_attn<1><<<nab, 256, 0, stream>>>(qb, hsb, kv8, srcd, We + l * HID,
                row_ptr, lng + l * HID, lnb + l * HID, hb, Wat, baf, out, NN);
        }
    }
}